// Round 1
// baseline (1033.163 us; speedup 1.0000x reference)
//
#include <hip/hip_runtime.h>
#include <math.h>

#define N_NODES 64000
#define N_EDGES 1048576
#define NB 1000
#define NG 64
#define NOUT 64

// ---------------- CSR build ----------------

__global__ void k_count(const int* __restrict__ dst, int* __restrict__ indeg) {
    int e = blockIdx.x * blockDim.x + threadIdx.x;
    if (e < N_EDGES) atomicAdd(&indeg[dst[e]], 1);
}

__global__ void k_dinv(const int* __restrict__ indeg, float* __restrict__ dinv) {
    int v = blockIdx.x * blockDim.x + threadIdx.x;
    if (v < N_NODES) dinv[v] = 1.0f / sqrtf((float)(indeg[v] + 1)); // +1 self loop
}

// single-block exclusive scan over 64000 ints -> rowptr + cursor copy
__global__ void k_scan(const int* __restrict__ indeg, int* __restrict__ rowptr,
                       int* __restrict__ cursor) {
    __shared__ int part[1024];
    int t = threadIdx.x;
    const int chunk = (N_NODES + 1023) / 1024; // 63
    int b = t * chunk;
    int sum = 0;
    for (int i = 0; i < chunk; ++i) { int idx = b + i; if (idx < N_NODES) sum += indeg[idx]; }
    part[t] = sum;
    __syncthreads();
    for (int off = 1; off < 1024; off <<= 1) {
        int other = (t >= off) ? part[t - off] : 0;
        __syncthreads();
        part[t] += other;
        __syncthreads();
    }
    int run = part[t] - sum; // exclusive offset of this chunk
    for (int i = 0; i < chunk; ++i) {
        int idx = b + i;
        if (idx < N_NODES) { rowptr[idx] = run; cursor[idx] = run; run += indeg[idx]; }
    }
    if (t == 1023) rowptr[N_NODES] = part[1023];
}

__global__ void k_fill(const int* __restrict__ src, const int* __restrict__ dst,
                       int* __restrict__ cursor, int* __restrict__ col) {
    int e = blockIdx.x * blockDim.x + threadIdx.x;
    if (e < N_EDGES) {
        int d = dst[e];
        int p = atomicAdd(&cursor[d], 1);
        col[p] = src[e];
    }
}

// ---------------- pull aggregation: out[v] = sum_{u->v} hl[u]*dinv[u]*dinv[v] + hl[v]*dinv[v]^2
// one wave per node; lane owns H/64 contiguous floats of the feature row.

template <int H, bool TANH>
__global__ void k_agg(const float* __restrict__ hl, float* __restrict__ op,
                      const int* __restrict__ rowptr, const int* __restrict__ col,
                      const float* __restrict__ dinv, const float* __restrict__ bias) {
    constexpr int VEC = H / 64;
    typedef float fvec __attribute__((ext_vector_type(VEC)));
    int lane = threadIdx.x & 63;
    int v = blockIdx.x * (blockDim.x >> 6) + (threadIdx.x >> 6);
    if (v >= N_NODES) return;
    float dv = dinv[v];
    fvec acc = *((const fvec*)(hl + (size_t)v * H) + lane) * (dv * dv); // self loop
    int beg = rowptr[v], end = rowptr[v + 1];
    for (int j = beg; j < end; j += 64) {
        int me = j + lane;
        int s = 0; float ds = 0.0f;
        if (me < end) { s = col[me]; ds = dinv[s]; }
        int cnt = min(64, end - j);
        for (int i = 0; i < cnt; ++i) {
            int ss = __shfl(s, i);
            float nrm = __shfl(ds, i) * dv;
            fvec r = *((const fvec*)(hl + (size_t)ss * H) + lane);
            acc += r * nrm;
        }
    }
    if (TANH) {
#pragma unroll
        for (int q = 0; q < VEC; ++q) acc[q] = tanhf(acc[q] + bias[lane * VEC + q]);
    }
    *((fvec*)(op + (size_t)v * H) + lane) = acc;
}

// ---------------- fp32 tiled GEMM: C[M,N] = A[M,K] @ B[K,N] (+bias, tanh)
// 64x64 tile per 256-thread block, 4x4 per thread, K-step 16.

__global__ void k_gemm(const float* __restrict__ A, const float* __restrict__ B,
                       const float* __restrict__ bias, float* __restrict__ C,
                       int K, int N, int do_tanh) {
    __shared__ float As[16][68];
    __shared__ float Bs[16][68];
    int t = threadIdx.x;
    int tx = t & 15, ty = t >> 4;
    int bm = blockIdx.x * 64, bn = blockIdx.y * 64;
    float acc[4][4] = {};
    for (int k0 = 0; k0 < K; k0 += 16) {
        int arow = t >> 2, ak = (t & 3) << 2;
        float4 va = *(const float4*)(A + (size_t)(bm + arow) * K + k0 + ak);
        As[ak + 0][arow] = va.x;
        As[ak + 1][arow] = va.y;
        As[ak + 2][arow] = va.z;
        As[ak + 3][arow] = va.w;
        int bk = t >> 4, bn4 = (t & 15) << 2;
        *(float4*)&Bs[bk][bn4] = *(const float4*)(B + (size_t)(k0 + bk) * N + bn + bn4);
        __syncthreads();
#pragma unroll
        for (int kk = 0; kk < 16; ++kk) {
            float4 a = *(const float4*)&As[kk][ty << 2];
            float4 b = *(const float4*)&Bs[kk][tx << 2];
            acc[0][0] += a.x * b.x; acc[0][1] += a.x * b.y; acc[0][2] += a.x * b.z; acc[0][3] += a.x * b.w;
            acc[1][0] += a.y * b.x; acc[1][1] += a.y * b.y; acc[1][2] += a.y * b.z; acc[1][3] += a.y * b.w;
            acc[2][0] += a.z * b.x; acc[2][1] += a.z * b.y; acc[2][2] += a.z * b.z; acc[2][3] += a.z * b.w;
            acc[3][0] += a.w * b.x; acc[3][1] += a.w * b.y; acc[3][2] += a.w * b.z; acc[3][3] += a.w * b.w;
        }
        __syncthreads();
    }
    float bv[4] = {0.f, 0.f, 0.f, 0.f};
    if (bias) {
#pragma unroll
        for (int j = 0; j < 4; ++j) bv[j] = bias[bn + (tx << 2) + j];
    }
#pragma unroll
    for (int i = 0; i < 4; ++i) {
        float4 r;
        r.x = acc[i][0] + bv[0];
        r.y = acc[i][1] + bv[1];
        r.z = acc[i][2] + bv[2];
        r.w = acc[i][3] + bv[3];
        if (do_tanh) { r.x = tanhf(r.x); r.y = tanhf(r.y); r.z = tanhf(r.z); r.w = tanhf(r.w); }
        *(float4*)&C[(size_t)(bm + (ty << 2) + i) * N + bn + (tx << 2)] = r;
    }
}

// ---------------- final FC: out[64,64] = h[64,128000] @ Wfc[128000,64] + bfc
// split-K: 64 blocks, each owns 2000 K rows, atomicAdd partials.

__global__ void k_init_out(const float* __restrict__ bfc, float* __restrict__ out) {
    int i = blockIdx.x * blockDim.x + threadIdx.x;
    if (i < NG * NOUT) out[i] = bfc[i & 63];
}

__global__ void k_fc(const float* __restrict__ A, const float* __restrict__ B,
                     float* __restrict__ out) {
    __shared__ float As[16][68];
    __shared__ float Bs[16][68];
    const int KROW = NB * 128;         // 128000
    const int KC = KROW / 64;          // 2000 per block
    int t = threadIdx.x;
    int tx = t & 15, ty = t >> 4;
    int k0b = blockIdx.x * KC;
    float acc[4][4] = {};
    for (int k0 = k0b; k0 < k0b + KC; k0 += 16) {
        int arow = t >> 2, ak = (t & 3) << 2;
        float4 va = *(const float4*)(A + (size_t)arow * KROW + k0 + ak);
        As[ak + 0][arow] = va.x;
        As[ak + 1][arow] = va.y;
        As[ak + 2][arow] = va.z;
        As[ak + 3][arow] = va.w;
        int bk = t >> 4, bn4 = (t & 15) << 2;
        *(float4*)&Bs[bk][bn4] = *(const float4*)(B + (size_t)(k0 + bk) * NOUT + bn4);
        __syncthreads();
#pragma unroll
        for (int kk = 0; kk < 16; ++kk) {
            float4 a = *(const float4*)&As[kk][ty << 2];
            float4 b = *(const float4*)&Bs[kk][tx << 2];
            acc[0][0] += a.x * b.x; acc[0][1] += a.x * b.y; acc[0][2] += a.x * b.z; acc[0][3] += a.x * b.w;
            acc[1][0] += a.y * b.x; acc[1][1] += a.y * b.y; acc[1][2] += a.y * b.z; acc[1][3] += a.y * b.w;
            acc[2][0] += a.z * b.x; acc[2][1] += a.z * b.y; acc[2][2] += a.z * b.z; acc[2][3] += a.z * b.w;
            acc[3][0] += a.w * b.x; acc[3][1] += a.w * b.y; acc[3][2] += a.w * b.z; acc[3][3] += a.w * b.w;
        }
        __syncthreads();
    }
#pragma unroll
    for (int i = 0; i < 4; ++i)
#pragma unroll
        for (int j = 0; j < 4; ++j)
            atomicAdd(&out[((ty << 2) + i) * NOUT + (tx << 2) + j], acc[i][j]);
}

// ---------------- driver ----------------

static inline size_t align256(size_t x) { return (x + 255) & ~(size_t)255; }

extern "C" void kernel_launch(void* const* d_in, const int* in_sizes, int n_in,
                              void* d_out, int out_size, void* d_ws, size_t ws_size,
                              hipStream_t stream) {
    const float* x   = (const float*)d_in[0];
    const int*   ei  = (const int*)d_in[1];
    const int*   src = ei;
    const int*   dst = ei + N_EDGES;
    const float* W1  = (const float*)d_in[3];
    const float* b1  = (const float*)d_in[4];
    const float* W2  = (const float*)d_in[5];
    const float* b2  = (const float*)d_in[6];
    const float* W3  = (const float*)d_in[7];
    const float* b3  = (const float*)d_in[8];
    const float* Wfc = (const float*)d_in[9];
    const float* bfc = (const float*)d_in[10];
    float* out = (float*)d_out;

    char* w = (char*)d_ws;
    float* B0 = (float*)w;      w += align256((size_t)N_NODES * 256 * 4);
    float* B1 = (float*)w;      w += align256((size_t)N_NODES * 256 * 4);
    int* indeg = (int*)w;       w += align256((size_t)N_NODES * 4);
    int* rowptr = (int*)w;      w += align256((size_t)(N_NODES + 1) * 4);
    int* cursor = (int*)w;      w += align256((size_t)N_NODES * 4);
    float* dinv = (float*)w;    w += align256((size_t)N_NODES * 4);
    int* col = (int*)w;         w += align256((size_t)N_EDGES * 4);

    // CSR build
    hipMemsetAsync(indeg, 0, (size_t)N_NODES * 4, stream);
    k_count<<<N_EDGES / 256, 256, 0, stream>>>(dst, indeg);
    k_dinv<<<(N_NODES + 255) / 256, 256, 0, stream>>>(indeg, dinv);
    k_scan<<<1, 1024, 0, stream>>>(indeg, rowptr, cursor);
    k_fill<<<N_EDGES / 256, 256, 0, stream>>>(src, dst, cursor, col);

    // layer 1: agg-first (H=128), then GEMM+bias+tanh -> 256
    k_agg<128, false><<<N_NODES / 4, 256, 0, stream>>>(x, B0, rowptr, col, dinv, nullptr);
    k_gemm<<<dim3(N_NODES / 64, 4), 256, 0, stream>>>(B0, W1, b1, B1, 128, 256, 1);

    // layer 2: agg (H=256), then GEMM+bias+tanh -> 256
    k_agg<256, false><<<N_NODES / 4, 256, 0, stream>>>(B1, B0, rowptr, col, dinv, nullptr);
    k_gemm<<<dim3(N_NODES / 64, 4), 256, 0, stream>>>(B0, W2, b2, B1, 256, 256, 1);

    // layer 3: GEMM-first (no epilogue), then agg (H=128) + bias + tanh
    k_gemm<<<dim3(N_NODES / 64, 2), 256, 0, stream>>>(B1, W3, nullptr, B0, 256, 128, 0);
    k_agg<128, true><<<N_NODES / 4, 256, 0, stream>>>(B0, B1, rowptr, col, dinv, b3);

    // final FC
    k_init_out<<<(NG * NOUT + 255) / 256, 256, 0, stream>>>(bfc, out);
    k_fc<<<64, 256, 0, stream>>>(B1, Wfc, out);
}

// Round 2
// 872.519 us; speedup vs baseline: 1.1841x; 1.1841x over previous
//
#include <hip/hip_runtime.h>
#include <math.h>

#define N_NODES 64000
#define N_EDGES 1048576
#define NB 1000
#define NG 64
#define NOUT 64
#define SCAN_BLOCKS 250   // 250 x 256 = 64000

// ---------------- CSR build ----------------

__global__ void k_count(const int* __restrict__ dst, int* __restrict__ indeg) {
    int e = blockIdx.x * blockDim.x + threadIdx.x;
    if (e < N_EDGES) atomicAdd(&indeg[dst[e]], 1);
}

// phase 1: per-block exclusive scan (256 elems), block sums out; fused dinv
__global__ void k_scan1(const int* __restrict__ indeg, int* __restrict__ local,
                        int* __restrict__ blocksum, float* __restrict__ dinv) {
    __shared__ int tmp[256];
    int t = threadIdx.x;
    int g = blockIdx.x * 256 + t;
    int v = indeg[g];                       // grid exactly covers N_NODES
    dinv[g] = rsqrtf((float)(v + 1));       // +1 self loop
    tmp[t] = v;
    __syncthreads();
    for (int off = 1; off < 256; off <<= 1) {
        int o = (t >= off) ? tmp[t - off] : 0;
        __syncthreads();
        tmp[t] += o;
        __syncthreads();
    }
    local[g] = tmp[t] - v;                  // exclusive
    if (t == 255) blocksum[blockIdx.x] = tmp[255];
}

// phase 2: single block scans the 250 block sums (exclusive, in place)
__global__ void k_scan2(int* __restrict__ blocksum) {
    __shared__ int tmp[256];
    int t = threadIdx.x;
    int v = (t < SCAN_BLOCKS) ? blocksum[t] : 0;
    tmp[t] = v;
    __syncthreads();
    for (int off = 1; off < 256; off <<= 1) {
        int o = (t >= off) ? tmp[t - off] : 0;
        __syncthreads();
        tmp[t] += o;
        __syncthreads();
    }
    if (t < SCAN_BLOCKS) blocksum[t] = tmp[t] - v;
}

// phase 3: add block offsets -> rowptr + cursor
__global__ void k_scan3(const int* __restrict__ local, const int* __restrict__ blocksum,
                        int* __restrict__ rowptr, int* __restrict__ cursor) {
    int g = blockIdx.x * 256 + threadIdx.x;
    int r = local[g] + blocksum[blockIdx.x];
    rowptr[g] = r;
    cursor[g] = r;
    if (g == 0) rowptr[N_NODES] = N_EDGES;  // total is statically known
}

__global__ void k_fill(const int* __restrict__ src, const int* __restrict__ dst,
                       int* __restrict__ cursor, int* __restrict__ col) {
    int e = blockIdx.x * blockDim.x + threadIdx.x;
    if (e < N_EDGES) {
        int d = dst[e];
        int p = atomicAdd(&cursor[d], 1);
        col[p] = src[e];
    }
}

// ---------------- pull aggregation: out[v] = sum_{u->v} hl[u]*dinv[u]*dinv[v] + hl[v]*dinv[v]^2
// one wave per node; lane owns H/64 contiguous floats of the feature row.

template <int H, bool TANH>
__global__ void k_agg(const float* __restrict__ hl, float* __restrict__ op,
                      const int* __restrict__ rowptr, const int* __restrict__ col,
                      const float* __restrict__ dinv, const float* __restrict__ bias) {
    constexpr int VEC = H / 64;
    typedef float fvec __attribute__((ext_vector_type(VEC)));
    int lane = threadIdx.x & 63;
    int v = blockIdx.x * (blockDim.x >> 6) + (threadIdx.x >> 6);
    if (v >= N_NODES) return;
    float dv = dinv[v];
    fvec acc = *((const fvec*)(hl + (size_t)v * H) + lane) * (dv * dv); // self loop
    int beg = rowptr[v], end = rowptr[v + 1];
    for (int j = beg; j < end; j += 64) {
        int me = j + lane;
        int s = 0; float ds = 0.0f;
        if (me < end) { s = col[me]; ds = dinv[s]; }
        int cnt = min(64, end - j);
        for (int i = 0; i < cnt; ++i) {
            int ss = __shfl(s, i);
            float nrm = __shfl(ds, i) * dv;
            fvec r = *((const fvec*)(hl + (size_t)ss * H) + lane);
            acc += r * nrm;
        }
    }
    if (TANH) {
#pragma unroll
        for (int q = 0; q < VEC; ++q) acc[q] = tanhf(acc[q] + bias[lane * VEC + q]);
    }
    *((fvec*)(op + (size_t)v * H) + lane) = acc;
}

// ---------------- fp32 tiled GEMM: C[M,N] = A[M,K] @ B[K,N] (+bias, tanh)
// 64x64 tile per 256-thread block, 4x4 per thread, K-step 16.

__global__ void k_gemm(const float* __restrict__ A, const float* __restrict__ B,
                       const float* __restrict__ bias, float* __restrict__ C,
                       int K, int N, int do_tanh) {
    __shared__ float As[16][68];
    __shared__ float Bs[16][68];
    int t = threadIdx.x;
    int tx = t & 15, ty = t >> 4;
    int bm = blockIdx.x * 64, bn = blockIdx.y * 64;
    float acc[4][4] = {};
    for (int k0 = 0; k0 < K; k0 += 16) {
        int arow = t >> 2, ak = (t & 3) << 2;
        float4 va = *(const float4*)(A + (size_t)(bm + arow) * K + k0 + ak);
        As[ak + 0][arow] = va.x;
        As[ak + 1][arow] = va.y;
        As[ak + 2][arow] = va.z;
        As[ak + 3][arow] = va.w;
        int bk = t >> 4, bn4 = (t & 15) << 2;
        *(float4*)&Bs[bk][bn4] = *(const float4*)(B + (size_t)(k0 + bk) * N + bn + bn4);
        __syncthreads();
#pragma unroll
        for (int kk = 0; kk < 16; ++kk) {
            float4 a = *(const float4*)&As[kk][ty << 2];
            float4 b = *(const float4*)&Bs[kk][tx << 2];
            acc[0][0] += a.x * b.x; acc[0][1] += a.x * b.y; acc[0][2] += a.x * b.z; acc[0][3] += a.x * b.w;
            acc[1][0] += a.y * b.x; acc[1][1] += a.y * b.y; acc[1][2] += a.y * b.z; acc[1][3] += a.y * b.w;
            acc[2][0] += a.z * b.x; acc[2][1] += a.z * b.y; acc[2][2] += a.z * b.z; acc[2][3] += a.z * b.w;
            acc[3][0] += a.w * b.x; acc[3][1] += a.w * b.y; acc[3][2] += a.w * b.z; acc[3][3] += a.w * b.w;
        }
        __syncthreads();
    }
    float bv[4] = {0.f, 0.f, 0.f, 0.f};
    if (bias) {
#pragma unroll
        for (int j = 0; j < 4; ++j) bv[j] = bias[bn + (tx << 2) + j];
    }
#pragma unroll
    for (int i = 0; i < 4; ++i) {
        float4 r;
        r.x = acc[i][0] + bv[0];
        r.y = acc[i][1] + bv[1];
        r.z = acc[i][2] + bv[2];
        r.w = acc[i][3] + bv[3];
        if (do_tanh) { r.x = tanhf(r.x); r.y = tanhf(r.y); r.z = tanhf(r.z); r.w = tanhf(r.w); }
        *(float4*)&C[(size_t)(bm + (ty << 2) + i) * N + bn + (tx << 2)] = r;
    }
}

// ---------------- final FC: out[64,64] = h[64,128000] @ Wfc[128000,64] + bfc
// split-K: 64 blocks, each owns 2000 K rows, atomicAdd partials.

__global__ void k_init_out(const float* __restrict__ bfc, float* __restrict__ out) {
    int i = blockIdx.x * blockDim.x + threadIdx.x;
    if (i < NG * NOUT) out[i] = bfc[i & 63];
}

__global__ void k_fc(const float* __restrict__ A, const float* __restrict__ B,
                     float* __restrict__ out) {
    __shared__ float As[16][68];
    __shared__ float Bs[16][68];
    const int KROW = NB * 128;         // 128000
    const int KC = KROW / 64;          // 2000 per block
    int t = threadIdx.x;
    int tx = t & 15, ty = t >> 4;
    int k0b = blockIdx.x * KC;
    float acc[4][4] = {};
    for (int k0 = k0b; k0 < k0b + KC; k0 += 16) {
        int arow = t >> 2, ak = (t & 3) << 2;
        float4 va = *(const float4*)(A + (size_t)arow * KROW + k0 + ak);
        As[ak + 0][arow] = va.x;
        As[ak + 1][arow] = va.y;
        As[ak + 2][arow] = va.z;
        As[ak + 3][arow] = va.w;
        int bk = t >> 4, bn4 = (t & 15) << 2;
        *(float4*)&Bs[bk][bn4] = *(const float4*)(B + (size_t)(k0 + bk) * NOUT + bn4);
        __syncthreads();
#pragma unroll
        for (int kk = 0; kk < 16; ++kk) {
            float4 a = *(const float4*)&As[kk][ty << 2];
            float4 b = *(const float4*)&Bs[kk][tx << 2];
            acc[0][0] += a.x * b.x; acc[0][1] += a.x * b.y; acc[0][2] += a.x * b.z; acc[0][3] += a.x * b.w;
            acc[1][0] += a.y * b.x; acc[1][1] += a.y * b.y; acc[1][2] += a.y * b.z; acc[1][3] += a.y * b.w;
            acc[2][0] += a.z * b.x; acc[2][1] += a.z * b.y; acc[2][2] += a.z * b.z; acc[2][3] += a.z * b.w;
            acc[3][0] += a.w * b.x; acc[3][1] += a.w * b.y; acc[3][2] += a.w * b.z; acc[3][3] += a.w * b.w;
        }
        __syncthreads();
    }
#pragma unroll
    for (int i = 0; i < 4; ++i)
#pragma unroll
        for (int j = 0; j < 4; ++j)
            atomicAdd(&out[((ty << 2) + i) * NOUT + (tx << 2) + j], acc[i][j]);
}

// ---------------- driver ----------------

static inline size_t align256(size_t x) { return (x + 255) & ~(size_t)255; }

extern "C" void kernel_launch(void* const* d_in, const int* in_sizes, int n_in,
                              void* d_out, int out_size, void* d_ws, size_t ws_size,
                              hipStream_t stream) {
    const float* x   = (const float*)d_in[0];
    const int*   ei  = (const int*)d_in[1];
    const int*   src = ei;
    const int*   dst = ei + N_EDGES;
    const float* W1  = (const float*)d_in[3];
    const float* b1  = (const float*)d_in[4];
    const float* W2  = (const float*)d_in[5];
    const float* b2  = (const float*)d_in[6];
    const float* W3  = (const float*)d_in[7];
    const float* b3  = (const float*)d_in[8];
    const float* Wfc = (const float*)d_in[9];
    const float* bfc = (const float*)d_in[10];
    float* out = (float*)d_out;

    char* w = (char*)d_ws;
    float* B0 = (float*)w;      w += align256((size_t)N_NODES * 256 * 4);
    float* B1 = (float*)w;      w += align256((size_t)N_NODES * 256 * 4);
    int* indeg = (int*)w;       w += align256((size_t)N_NODES * 4);
    int* rowptr = (int*)w;      w += align256((size_t)(N_NODES + 1) * 4);
    int* cursor = (int*)w;      w += align256((size_t)N_NODES * 4);
    float* dinv = (float*)w;    w += align256((size_t)N_NODES * 4);
    int* col = (int*)w;         w += align256((size_t)N_EDGES * 4);
    int* slocal = (int*)w;      w += align256((size_t)N_NODES * 4);
    int* sblock = (int*)w;      w += align256((size_t)SCAN_BLOCKS * 4);

    // CSR build (multi-block scan: ~5 us total vs 160 us single-block)
    hipMemsetAsync(indeg, 0, (size_t)N_NODES * 4, stream);
    k_count<<<N_EDGES / 256, 256, 0, stream>>>(dst, indeg);
    k_scan1<<<SCAN_BLOCKS, 256, 0, stream>>>(indeg, slocal, sblock, dinv);
    k_scan2<<<1, 256, 0, stream>>>(sblock);
    k_scan3<<<SCAN_BLOCKS, 256, 0, stream>>>(slocal, sblock, rowptr, cursor);
    k_fill<<<N_EDGES / 256, 256, 0, stream>>>(src, dst, cursor, col);

    // layer 1: agg-first (H=128), then GEMM+bias+tanh -> 256
    k_agg<128, false><<<N_NODES / 4, 256, 0, stream>>>(x, B0, rowptr, col, dinv, nullptr);
    k_gemm<<<dim3(N_NODES / 64, 4), 256, 0, stream>>>(B0, W1, b1, B1, 128, 256, 1);

    // layer 2: agg (H=256), then GEMM+bias+tanh -> 256
    k_agg<256, false><<<N_NODES / 4, 256, 0, stream>>>(B1, B0, rowptr, col, dinv, nullptr);
    k_gemm<<<dim3(N_NODES / 64, 4), 256, 0, stream>>>(B0, W2, b2, B1, 256, 256, 1);

    // layer 3: GEMM-first (no epilogue), then agg (H=128) + bias + tanh
    k_gemm<<<dim3(N_NODES / 64, 2), 256, 0, stream>>>(B1, W3, nullptr, B0, 256, 128, 0);
    k_agg<128, true><<<N_NODES / 4, 256, 0, stream>>>(B0, B1, rowptr, col, dinv, b3);

    // final FC
    k_init_out<<<(NG * NOUT + 255) / 256, 256, 0, stream>>>(bfc, out);
    k_fc<<<64, 256, 0, stream>>>(B1, Wfc, out);
}

// Round 3
// 772.741 us; speedup vs baseline: 1.3370x; 1.1291x over previous
//
#include <hip/hip_runtime.h>
#include <math.h>

#define N_NODES 64000
#define N_EDGES 1048576
#define NB 1000
#define NG 64
#define NOUT 64
#define SCAN_BLOCKS 250   // 250 x 256 = 64000
#define FC_SPLIT 500      // 500 x 256 = 128000 K-rows

// ---------------- CSR build ----------------

__global__ void k_count(const int* __restrict__ dst, int* __restrict__ indeg) {
    int e = blockIdx.x * blockDim.x + threadIdx.x;
    if (e < N_EDGES) atomicAdd(&indeg[dst[e]], 1);
}

// phase 1: per-block exclusive scan (256 elems), block sums out; fused dinv
__global__ void k_scan1(const int* __restrict__ indeg, int* __restrict__ local,
                        int* __restrict__ blocksum, float* __restrict__ dinv) {
    __shared__ int tmp[256];
    int t = threadIdx.x;
    int g = blockIdx.x * 256 + t;
    int v = indeg[g];                       // grid exactly covers N_NODES
    dinv[g] = rsqrtf((float)(v + 1));       // +1 self loop
    tmp[t] = v;
    __syncthreads();
    for (int off = 1; off < 256; off <<= 1) {
        int o = (t >= off) ? tmp[t - off] : 0;
        __syncthreads();
        tmp[t] += o;
        __syncthreads();
    }
    local[g] = tmp[t] - v;                  // exclusive
    if (t == 255) blocksum[blockIdx.x] = tmp[255];
}

// phase 2: single block scans the 250 block sums (exclusive, in place)
__global__ void k_scan2(int* __restrict__ blocksum) {
    __shared__ int tmp[256];
    int t = threadIdx.x;
    int v = (t < SCAN_BLOCKS) ? blocksum[t] : 0;
    tmp[t] = v;
    __syncthreads();
    for (int off = 1; off < 256; off <<= 1) {
        int o = (t >= off) ? tmp[t - off] : 0;
        __syncthreads();
        tmp[t] += o;
        __syncthreads();
    }
    if (t < SCAN_BLOCKS) blocksum[t] = tmp[t] - v;
}

// phase 3: add block offsets -> rowptr + cursor
__global__ void k_scan3(const int* __restrict__ local, const int* __restrict__ blocksum,
                        int* __restrict__ rowptr, int* __restrict__ cursor) {
    int g = blockIdx.x * 256 + threadIdx.x;
    int r = local[g] + blocksum[blockIdx.x];
    rowptr[g] = r;
    cursor[g] = r;
    if (g == 0) rowptr[N_NODES] = N_EDGES;  // total is statically known
}

__global__ void k_fill(const int* __restrict__ src, const int* __restrict__ dst,
                       int* __restrict__ cursor, int* __restrict__ col) {
    int e = blockIdx.x * blockDim.x + threadIdx.x;
    if (e < N_EDGES) {
        int d = dst[e];
        int p = atomicAdd(&cursor[d], 1);
        col[p] = src[e];
    }
}

// ---------------- pull aggregation: out[v] = sum_{u->v} hl[u]*dinv[u]*dinv[v] + hl[v]*dinv[v]^2
// one wave per node; lane owns H/64 contiguous floats of the feature row.

template <int H, bool TANH>
__global__ void k_agg(const float* __restrict__ hl, float* __restrict__ op,
                      const int* __restrict__ rowptr, const int* __restrict__ col,
                      const float* __restrict__ dinv, const float* __restrict__ bias) {
    constexpr int VEC = H / 64;
    typedef float fvec __attribute__((ext_vector_type(VEC)));
    int lane = threadIdx.x & 63;
    int v = blockIdx.x * (blockDim.x >> 6) + (threadIdx.x >> 6);
    if (v >= N_NODES) return;
    float dv = dinv[v];
    fvec acc = *((const fvec*)(hl + (size_t)v * H) + lane) * (dv * dv); // self loop
    int beg = rowptr[v], end = rowptr[v + 1];
    for (int j = beg; j < end; j += 64) {
        int me = j + lane;
        int s = 0; float ds = 0.0f;
        if (me < end) { s = col[me]; ds = dinv[s]; }
        int cnt = min(64, end - j);
        for (int i = 0; i < cnt; ++i) {
            int ss = __shfl(s, i);
            float nrm = __shfl(ds, i) * dv;
            fvec r = *((const fvec*)(hl + (size_t)ss * H) + lane);
            acc += r * nrm;
        }
    }
    if (TANH) {
#pragma unroll
        for (int q = 0; q < VEC; ++q) acc[q] = tanhf(acc[q] + bias[lane * VEC + q]);
    }
    *((fvec*)(op + (size_t)v * H) + lane) = acc;
}

// ---------------- fp32 tiled GEMM: C[M,N] = A[M,K] @ B[K,N] (+bias, tanh)
// 64x64 tile per 256-thread block, 4x4 per thread, K-step 16.

__global__ void k_gemm(const float* __restrict__ A, const float* __restrict__ B,
                       const float* __restrict__ bias, float* __restrict__ C,
                       int K, int N, int do_tanh) {
    __shared__ float As[16][68];
    __shared__ float Bs[16][68];
    int t = threadIdx.x;
    int tx = t & 15, ty = t >> 4;
    int bm = blockIdx.x * 64, bn = blockIdx.y * 64;
    float acc[4][4] = {};
    for (int k0 = 0; k0 < K; k0 += 16) {
        int arow = t >> 2, ak = (t & 3) << 2;
        float4 va = *(const float4*)(A + (size_t)(bm + arow) * K + k0 + ak);
        As[ak + 0][arow] = va.x;
        As[ak + 1][arow] = va.y;
        As[ak + 2][arow] = va.z;
        As[ak + 3][arow] = va.w;
        int bk = t >> 4, bn4 = (t & 15) << 2;
        *(float4*)&Bs[bk][bn4] = *(const float4*)(B + (size_t)(k0 + bk) * N + bn + bn4);
        __syncthreads();
#pragma unroll
        for (int kk = 0; kk < 16; ++kk) {
            float4 a = *(const float4*)&As[kk][ty << 2];
            float4 b = *(const float4*)&Bs[kk][tx << 2];
            acc[0][0] += a.x * b.x; acc[0][1] += a.x * b.y; acc[0][2] += a.x * b.z; acc[0][3] += a.x * b.w;
            acc[1][0] += a.y * b.x; acc[1][1] += a.y * b.y; acc[1][2] += a.y * b.z; acc[1][3] += a.y * b.w;
            acc[2][0] += a.z * b.x; acc[2][1] += a.z * b.y; acc[2][2] += a.z * b.z; acc[2][3] += a.z * b.w;
            acc[3][0] += a.w * b.x; acc[3][1] += a.w * b.y; acc[3][2] += a.w * b.z; acc[3][3] += a.w * b.w;
        }
        __syncthreads();
    }
    float bv[4] = {0.f, 0.f, 0.f, 0.f};
    if (bias) {
#pragma unroll
        for (int j = 0; j < 4; ++j) bv[j] = bias[bn + (tx << 2) + j];
    }
#pragma unroll
    for (int i = 0; i < 4; ++i) {
        float4 r;
        r.x = acc[i][0] + bv[0];
        r.y = acc[i][1] + bv[1];
        r.z = acc[i][2] + bv[2];
        r.w = acc[i][3] + bv[3];
        if (do_tanh) { r.x = tanhf(r.x); r.y = tanhf(r.y); r.z = tanhf(r.z); r.w = tanhf(r.w); }
        *(float4*)&C[(size_t)(bm + (ty << 2) + i) * N + bn + (tx << 2)] = r;
    }
}

// ---------------- final FC: out[64,64] = h[64,128000] @ Wfc[128000,64] + bfc
// split-K over 500 blocks x 256 K-rows; partials to ws, then reduce.

__global__ void k_fc(const float* __restrict__ A, const float* __restrict__ B,
                     float* __restrict__ part) {
    __shared__ float As[16][68];
    __shared__ float Bs[16][68];
    const int KROW = NB * 128;         // 128000
    int t = threadIdx.x;
    int tx = t & 15, ty = t >> 4;
    int k0b = blockIdx.x * 256;        // this block's K range
    float acc[4][4] = {};
    for (int k0 = k0b; k0 < k0b + 256; k0 += 16) {
        int arow = t >> 2, ak = (t & 3) << 2;
        float4 va = *(const float4*)(A + (size_t)arow * KROW + k0 + ak);
        As[ak + 0][arow] = va.x;
        As[ak + 1][arow] = va.y;
        As[ak + 2][arow] = va.z;
        As[ak + 3][arow] = va.w;
        int bk = t >> 4, bn4 = (t & 15) << 2;
        *(float4*)&Bs[bk][bn4] = *(const float4*)(B + (size_t)(k0 + bk) * NOUT + bn4);
        __syncthreads();
#pragma unroll
        for (int kk = 0; kk < 16; ++kk) {
            float4 a = *(const float4*)&As[kk][ty << 2];
            float4 b = *(const float4*)&Bs[kk][tx << 2];
            acc[0][0] += a.x * b.x; acc[0][1] += a.x * b.y; acc[0][2] += a.x * b.z; acc[0][3] += a.x * b.w;
            acc[1][0] += a.y * b.x; acc[1][1] += a.y * b.y; acc[1][2] += a.y * b.z; acc[1][3] += a.y * b.w;
            acc[2][0] += a.z * b.x; acc[2][1] += a.z * b.y; acc[2][2] += a.z * b.z; acc[2][3] += a.z * b.w;
            acc[3][0] += a.w * b.x; acc[3][1] += a.w * b.y; acc[3][2] += a.w * b.z; acc[3][3] += a.w * b.w;
        }
        __syncthreads();
    }
    float* po = part + (size_t)blockIdx.x * (NG * NOUT);
#pragma unroll
    for (int i = 0; i < 4; ++i) {
        float4 r;
        r.x = acc[i][0]; r.y = acc[i][1]; r.z = acc[i][2]; r.w = acc[i][3];
        *(float4*)&po[((ty << 2) + i) * NOUT + (tx << 2)] = r;
    }
}

__global__ void k_fc_reduce(const float* __restrict__ part, const float* __restrict__ bfc,
                            float* __restrict__ out) {
    int i = blockIdx.x * blockDim.x + threadIdx.x;   // 4096 threads
    float s = bfc[i & 63];
    for (int b = 0; b < FC_SPLIT; ++b) s += part[(size_t)b * (NG * NOUT) + i];
    out[i] = s;
}

// ---------------- driver ----------------

static inline size_t align256(size_t x) { return (x + 255) & ~(size_t)255; }

extern "C" void kernel_launch(void* const* d_in, const int* in_sizes, int n_in,
                              void* d_out, int out_size, void* d_ws, size_t ws_size,
                              hipStream_t stream) {
    const float* x   = (const float*)d_in[0];
    const int*   ei  = (const int*)d_in[1];
    const int*   src = ei;
    const int*   dst = ei + N_EDGES;
    const float* W1  = (const float*)d_in[3];
    const float* b1  = (const float*)d_in[4];
    const float* W2  = (const float*)d_in[5];
    const float* b2  = (const float*)d_in[6];
    const float* W3  = (const float*)d_in[7];
    const float* b3  = (const float*)d_in[8];
    const float* Wfc = (const float*)d_in[9];
    const float* bfc = (const float*)d_in[10];
    float* out = (float*)d_out;

    char* w = (char*)d_ws;
    float* B0 = (float*)w;      w += align256((size_t)N_NODES * 256 * 4);
    float* B1 = (float*)w;      w += align256((size_t)N_NODES * 256 * 4);
    int* indeg = (int*)w;       w += align256((size_t)N_NODES * 4);
    int* rowptr = (int*)w;      w += align256((size_t)(N_NODES + 1) * 4);
    int* cursor = (int*)w;      w += align256((size_t)N_NODES * 4);
    float* dinv = (float*)w;    w += align256((size_t)N_NODES * 4);
    int* col = (int*)w;         w += align256((size_t)N_EDGES * 4);
    int* slocal = (int*)w;      w += align256((size_t)N_NODES * 4);
    int* sblock = (int*)w;      w += align256((size_t)SCAN_BLOCKS * 4);
    float* fcpart = (float*)w;  w += align256((size_t)FC_SPLIT * NG * NOUT * 4);

    // CSR build (multi-block scan)
    hipMemsetAsync(indeg, 0, (size_t)N_NODES * 4, stream);
    k_count<<<N_EDGES / 256, 256, 0, stream>>>(dst, indeg);
    k_scan1<<<SCAN_BLOCKS, 256, 0, stream>>>(indeg, slocal, sblock, dinv);
    k_scan2<<<1, 256, 0, stream>>>(sblock);
    k_scan3<<<SCAN_BLOCKS, 256, 0, stream>>>(slocal, sblock, rowptr, cursor);
    k_fill<<<N_EDGES / 256, 256, 0, stream>>>(src, dst, cursor, col);

    // layer 1: agg-first (H=128), then GEMM+bias+tanh -> 256
    k_agg<128, false><<<N_NODES / 4, 256, 0, stream>>>(x, B0, rowptr, col, dinv, nullptr);
    k_gemm<<<dim3(N_NODES / 64, 4), 256, 0, stream>>>(B0, W1, b1, B1, 128, 256, 1);

    // layer 2: agg (H=256), then GEMM+bias+tanh -> 256
    k_agg<256, false><<<N_NODES / 4, 256, 0, stream>>>(B1, B0, rowptr, col, dinv, nullptr);
    k_gemm<<<dim3(N_NODES / 64, 4), 256, 0, stream>>>(B0, W2, b2, B1, 256, 256, 1);

    // layer 3: GEMM-first (no epilogue), then agg (H=128) + bias + tanh
    k_gemm<<<dim3(N_NODES / 64, 2), 256, 0, stream>>>(B1, W3, nullptr, B0, 256, 128, 0);
    k_agg<128, true><<<N_NODES / 4, 256, 0, stream>>>(B0, B1, rowptr, col, dinv, b3);

    // final FC: split-K partials + reduce
    k_fc<<<FC_SPLIT, 256, 0, stream>>>(B1, Wfc, fcpart);
    k_fc_reduce<<<NG * NOUT / 256, 256, 0, stream>>>(fcpart, bfc, out);
}

// Round 4
// 562.194 us; speedup vs baseline: 1.8377x; 1.3745x over previous
//
#include <hip/hip_runtime.h>
#include <math.h>

#define N_NODES 64000
#define N_EDGES 1048576
#define NB 1000
#define NG 64
#define NOUT 64
#define SCAN_BLOCKS 250   // 250 x 256 = 64000
#define FC_SPLIT 500      // 500 x 256 = 128000 K-rows

typedef __attribute__((ext_vector_type(8))) short bfrag;   // 8 bf16 = 4 VGPRs
typedef __attribute__((ext_vector_type(4))) float f32x4;

__device__ inline float bf2f(unsigned short u) {
    union { unsigned int i; float f; } x; x.i = ((unsigned int)u) << 16; return x.f;
}
__device__ inline unsigned short f2bf(float f) {   // round-to-nearest-even
    union { float f; unsigned int i; } x; x.f = f;
    return (unsigned short)((x.i + 0x7FFFu + ((x.i >> 16) & 1u)) >> 16);
}

// ---------------- CSR build ----------------

__global__ void k_count(const int* __restrict__ dst, int* __restrict__ indeg) {
    int e = blockIdx.x * blockDim.x + threadIdx.x;
    if (e < N_EDGES) atomicAdd(&indeg[dst[e]], 1);
}

__global__ void k_scan1(const int* __restrict__ indeg, int* __restrict__ local,
                        int* __restrict__ blocksum, float* __restrict__ dinv) {
    __shared__ int tmp[256];
    int t = threadIdx.x;
    int g = blockIdx.x * 256 + t;
    int v = indeg[g];
    dinv[g] = rsqrtf((float)(v + 1));       // +1 self loop
    tmp[t] = v;
    __syncthreads();
    for (int off = 1; off < 256; off <<= 1) {
        int o = (t >= off) ? tmp[t - off] : 0;
        __syncthreads();
        tmp[t] += o;
        __syncthreads();
    }
    local[g] = tmp[t] - v;
    if (t == 255) blocksum[blockIdx.x] = tmp[255];
}

__global__ void k_scan2(int* __restrict__ blocksum) {
    __shared__ int tmp[256];
    int t = threadIdx.x;
    int v = (t < SCAN_BLOCKS) ? blocksum[t] : 0;
    tmp[t] = v;
    __syncthreads();
    for (int off = 1; off < 256; off <<= 1) {
        int o = (t >= off) ? tmp[t - off] : 0;
        __syncthreads();
        tmp[t] += o;
        __syncthreads();
    }
    if (t < SCAN_BLOCKS) blocksum[t] = tmp[t] - v;
}

__global__ void k_scan3(const int* __restrict__ local, const int* __restrict__ blocksum,
                        int* __restrict__ rowptr, int* __restrict__ cursor) {
    int g = blockIdx.x * 256 + threadIdx.x;
    int r = local[g] + blocksum[blockIdx.x];
    rowptr[g] = r;
    cursor[g] = r;
    if (g == 0) rowptr[N_NODES] = N_EDGES;
}

__global__ void k_fill(const int* __restrict__ src, const int* __restrict__ dst,
                       int* __restrict__ cursor, int* __restrict__ col) {
    int e = blockIdx.x * blockDim.x + threadIdx.x;
    if (e < N_EDGES) {
        int d = dst[e];
        int p = atomicAdd(&cursor[d], 1);
        col[p] = src[e];
    }
}

// ---------------- casts ----------------

// fp32 -> bf16, n multiple of 4
__global__ void k_cast(const float* __restrict__ in, unsigned short* __restrict__ out) {
    int i = (blockIdx.x * blockDim.x + threadIdx.x) * 4;
    float4 v = *(const float4*)(in + i);
    union { unsigned short s[4]; uint2 u; } o;
    o.s[0] = f2bf(v.x); o.s[1] = f2bf(v.y); o.s[2] = f2bf(v.z); o.s[3] = f2bf(v.w);
    *(uint2*)(out + i) = o.u;
}

// W[K][N] fp32 -> Wt[N][K] bf16
__global__ void k_wt(const float* __restrict__ W, unsigned short* __restrict__ Wt,
                     int K, int N) {
    int i = blockIdx.x * 256 + threadIdx.x;
    if (i < K * N) {
        int n = i / K, k = i % K;
        Wt[i] = f2bf(W[k * N + n]);
    }
}

// ---------------- pull aggregation (bf16 in / bf16 out, fp32 math) ----------------
// out[v] = sum_{u->v} hl[u]*dinv[u]*dinv[v] + hl[v]*dinv[v]^2 (+bias,tanh)

template <int H, bool TANH>
__global__ void k_agg(const unsigned short* __restrict__ hl, unsigned short* __restrict__ op,
                      const int* __restrict__ rowptr, const int* __restrict__ col,
                      const float* __restrict__ dinv, const float* __restrict__ bias) {
    constexpr int VEC = H / 64;  // 2 (H=128) or 4 (H=256) bf16 per lane
    int lane = threadIdx.x & 63;
    int v = blockIdx.x * (blockDim.x >> 6) + (threadIdx.x >> 6);
    if (v >= N_NODES) return;
    float dv = dinv[v];
    float acc[VEC];
    {
        const unsigned short* r = hl + (size_t)v * H + lane * VEC;
        float dv2 = dv * dv;
        if (VEC == 2) {
            unsigned int u = *(const unsigned int*)r;
            acc[0] = bf2f((unsigned short)(u & 0xffff)) * dv2;
            acc[1] = bf2f((unsigned short)(u >> 16)) * dv2;
        } else {
            uint2 u = *(const uint2*)r;
            acc[0] = bf2f((unsigned short)(u.x & 0xffff)) * dv2;
            acc[1] = bf2f((unsigned short)(u.x >> 16)) * dv2;
            acc[2] = bf2f((unsigned short)(u.y & 0xffff)) * dv2;
            acc[3] = bf2f((unsigned short)(u.y >> 16)) * dv2;
        }
    }
    int beg = rowptr[v], end = rowptr[v + 1];
    for (int j = beg; j < end; j += 64) {
        int me = j + lane;
        int s = 0; float ds = 0.0f;
        if (me < end) { s = col[me]; ds = dinv[s]; }
        int cnt = min(64, end - j);
        for (int i = 0; i < cnt; ++i) {
            int ss = __shfl(s, i);
            float nrm = __shfl(ds, i) * dv;
            const unsigned short* r = hl + (size_t)ss * H + lane * VEC;
            if (VEC == 2) {
                unsigned int u = *(const unsigned int*)r;
                acc[0] += bf2f((unsigned short)(u & 0xffff)) * nrm;
                acc[1] += bf2f((unsigned short)(u >> 16)) * nrm;
            } else {
                uint2 u = *(const uint2*)r;
                acc[0] += bf2f((unsigned short)(u.x & 0xffff)) * nrm;
                acc[1] += bf2f((unsigned short)(u.x >> 16)) * nrm;
                acc[2] += bf2f((unsigned short)(u.y & 0xffff)) * nrm;
                acc[3] += bf2f((unsigned short)(u.y >> 16)) * nrm;
            }
        }
    }
    if (TANH) {
#pragma unroll
        for (int q = 0; q < VEC; ++q) acc[q] = tanhf(acc[q] + bias[lane * VEC + q]);
    }
    unsigned short* o = op + (size_t)v * H + lane * VEC;
    if (VEC == 2) {
        union { unsigned short s[2]; unsigned int u; } pk;
        pk.s[0] = f2bf(acc[0]); pk.s[1] = f2bf(acc[1]);
        *(unsigned int*)o = pk.u;
    } else {
        union { unsigned short s[4]; uint2 u; } pk;
        pk.s[0] = f2bf(acc[0]); pk.s[1] = f2bf(acc[1]);
        pk.s[2] = f2bf(acc[2]); pk.s[3] = f2bf(acc[3]);
        *(uint2*)o = pk.u;
    }
}

// ---------------- bf16 MFMA GEMM: C[M,N] = A[M,K] @ W[K,N], Wt pre-transposed [N][K]
// 256 threads = 4 waves, each wave 64x64 (4x4 tiles of 16x16x32). No LDS:
// per-lane contiguous 16B fragment loads (A row-major, Wt row-major), L1-broadcast.
// WM x WN = wave grid (WM*WN=4); block covers WM*64 rows x WN*64 cols.

template <int K, int N, int WM, int WN, bool TB>
__global__ __launch_bounds__(256) void k_gemm_mfma(const unsigned short* __restrict__ A,
                                                   const unsigned short* __restrict__ Wt,
                                                   const float* __restrict__ bias,
                                                   unsigned short* __restrict__ C) {
    int w = threadIdx.x >> 6, l = threadIdx.x & 63;
    int lm = l & 15, lq = l >> 4;
    int wm = w / WN, wn = w % WN;
    int m0 = blockIdx.x * (WM * 64) + wm * 64;
    int n0 = wn * 64;
    f32x4 acc[4][4] = {};
    const unsigned short* Ab = A + (size_t)(m0 + lm) * K + lq * 8;
    const unsigned short* Bb = Wt + (size_t)(n0 + lm) * K + lq * 8;
#pragma unroll 2
    for (int ks = 0; ks < K; ks += 32) {
        bfrag af[4], bf[4];
#pragma unroll
        for (int i = 0; i < 4; ++i) af[i] = *(const bfrag*)(Ab + (size_t)i * 16 * K + ks);
#pragma unroll
        for (int j = 0; j < 4; ++j) bf[j] = *(const bfrag*)(Bb + (size_t)j * 16 * K + ks);
#pragma unroll
        for (int i = 0; i < 4; ++i)
#pragma unroll
            for (int j = 0; j < 4; ++j)
                acc[i][j] = __builtin_amdgcn_mfma_f32_16x16x32_bf16(af[i], bf[j], acc[i][j], 0, 0, 0);
    }
    float bj[4];
    if (TB) {
#pragma unroll
        for (int j = 0; j < 4; ++j) bj[j] = bias[n0 + j * 16 + lm];
    }
    int row0 = lq * 4;
#pragma unroll
    for (int i = 0; i < 4; ++i)
#pragma unroll
        for (int j = 0; j < 4; ++j) {
#pragma unroll
            for (int r = 0; r < 4; ++r) {
                float v = acc[i][j][r];
                if (TB) v = tanhf(v + bj[j]);
                C[(size_t)(m0 + i * 16 + row0 + r) * N + n0 + j * 16 + lm] = f2bf(v);
            }
        }
}

// ---------------- final FC: out[64,64] = h[64,128000](bf16) @ Wfc[128000,64](f32) + bfc
// split-K over 500 blocks x 256 K-rows; partials to ws, then reduce.

__global__ void k_fc(const unsigned short* __restrict__ A, const float* __restrict__ B,
                     float* __restrict__ part) {
    __shared__ float As[16][68];
    __shared__ float Bs[16][68];
    const int KROW = NB * 128;         // 128000
    int t = threadIdx.x;
    int tx = t & 15, ty = t >> 4;
    int k0b = blockIdx.x * 256;
    float acc[4][4] = {};
    for (int k0 = k0b; k0 < k0b + 256; k0 += 16) {
        int arow = t >> 2, ak = (t & 3) << 2;
        uint2 ua = *(const uint2*)(A + (size_t)arow * KROW + k0 + ak);
        As[ak + 0][arow] = bf2f((unsigned short)(ua.x & 0xffff));
        As[ak + 1][arow] = bf2f((unsigned short)(ua.x >> 16));
        As[ak + 2][arow] = bf2f((unsigned short)(ua.y & 0xffff));
        As[ak + 3][arow] = bf2f((unsigned short)(ua.y >> 16));
        int bk = t >> 4, bn4 = (t & 15) << 2;
        *(float4*)&Bs[bk][bn4] = *(const float4*)(B + (size_t)(k0 + bk) * NOUT + bn4);
        __syncthreads();
#pragma unroll
        for (int kk = 0; kk < 16; ++kk) {
            float4 a = *(const float4*)&As[kk][ty << 2];
            float4 b = *(const float4*)&Bs[kk][tx << 2];
            acc[0][0] += a.x * b.x; acc[0][1] += a.x * b.y; acc[0][2] += a.x * b.z; acc[0][3] += a.x * b.w;
            acc[1][0] += a.y * b.x; acc[1][1] += a.y * b.y; acc[1][2] += a.y * b.z; acc[1][3] += a.y * b.w;
            acc[2][0] += a.z * b.x; acc[2][1] += a.z * b.y; acc[2][2] += a.z * b.z; acc[2][3] += a.z * b.w;
            acc[3][0] += a.w * b.x; acc[3][1] += a.w * b.y; acc[3][2] += a.w * b.z; acc[3][3] += a.w * b.w;
        }
        __syncthreads();
    }
    float* po = part + (size_t)blockIdx.x * (NG * NOUT);
#pragma unroll
    for (int i = 0; i < 4; ++i) {
        float4 r;
        r.x = acc[i][0]; r.y = acc[i][1]; r.z = acc[i][2]; r.w = acc[i][3];
        *(float4*)&po[((ty << 2) + i) * NOUT + (tx << 2)] = r;
    }
}

__global__ void k_fc_reduce(const float* __restrict__ part, const float* __restrict__ bfc,
                            float* __restrict__ out) {
    int i = blockIdx.x * blockDim.x + threadIdx.x;   // 4096 threads
    float s = bfc[i & 63];
    for (int b = 0; b < FC_SPLIT; ++b) s += part[(size_t)b * (NG * NOUT) + i];
    out[i] = s;
}

// ---------------- driver ----------------

static inline size_t align256(size_t x) { return (x + 255) & ~(size_t)255; }

extern "C" void kernel_launch(void* const* d_in, const int* in_sizes, int n_in,
                              void* d_out, int out_size, void* d_ws, size_t ws_size,
                              hipStream_t stream) {
    const float* x   = (const float*)d_in[0];
    const int*   ei  = (const int*)d_in[1];
    const int*   src = ei;
    const int*   dst = ei + N_EDGES;
    const float* W1  = (const float*)d_in[3];
    const float* b1  = (const float*)d_in[4];
    const float* W2  = (const float*)d_in[5];
    const float* b2  = (const float*)d_in[6];
    const float* W3  = (const float*)d_in[7];
    const float* b3  = (const float*)d_in[8];
    const float* Wfc = (const float*)d_in[9];
    const float* bfc = (const float*)d_in[10];
    float* out = (float*)d_out;

    char* w = (char*)d_ws;
    unsigned short* P0 = (unsigned short*)w; w += align256((size_t)N_NODES * 256 * 2);
    unsigned short* P1 = (unsigned short*)w; w += align256((size_t)N_NODES * 256 * 2);
    unsigned short* P2 = (unsigned short*)w; w += align256((size_t)N_NODES * 256 * 2);
    int* indeg = (int*)w;       w += align256((size_t)N_NODES * 4);
    int* rowptr = (int*)w;      w += align256((size_t)(N_NODES + 1) * 4);
    int* cursor = (int*)w;      w += align256((size_t)N_NODES * 4);
    float* dinv = (float*)w;    w += align256((size_t)N_NODES * 4);
    int* col = (int*)w;         w += align256((size_t)N_EDGES * 4);
    int* slocal = (int*)w;      w += align256((size_t)N_NODES * 4);
    int* sblock = (int*)w;      w += align256((size_t)SCAN_BLOCKS * 4);
    float* fcpart = (float*)w;  w += align256((size_t)FC_SPLIT * NG * NOUT * 4);
    unsigned short* W1t = (unsigned short*)w; w += align256((size_t)128 * 256 * 2);
    unsigned short* W2t = (unsigned short*)w; w += align256((size_t)256 * 256 * 2);
    unsigned short* W3t = (unsigned short*)w; w += align256((size_t)256 * 128 * 2);

    // CSR build
    hipMemsetAsync(indeg, 0, (size_t)N_NODES * 4, stream);
    k_count<<<N_EDGES / 256, 256, 0, stream>>>(dst, indeg);
    k_scan1<<<SCAN_BLOCKS, 256, 0, stream>>>(indeg, slocal, sblock, dinv);
    k_scan2<<<1, 256, 0, stream>>>(sblock);
    k_scan3<<<SCAN_BLOCKS, 256, 0, stream>>>(slocal, sblock, rowptr, cursor);
    k_fill<<<N_EDGES / 256, 256, 0, stream>>>(src, dst, cursor, col);

    // casts: x -> bf16 (into P0), weights -> transposed bf16
    k_cast<<<(N_NODES * 128 / 4) / 256, 256, 0, stream>>>(x, P0);
    k_wt<<<(128 * 256 + 255) / 256, 256, 0, stream>>>(W1, W1t, 128, 256);
    k_wt<<<(256 * 256 + 255) / 256, 256, 0, stream>>>(W2, W2t, 256, 256);
    k_wt<<<(256 * 128 + 255) / 256, 256, 0, stream>>>(W3, W3t, 256, 128);

    // layer 1: agg(H=128) then MFMA gemm + bias + tanh -> 256
    k_agg<128, false><<<N_NODES / 4, 256, 0, stream>>>(P0, P1, rowptr, col, dinv, nullptr);
    k_gemm_mfma<128, 256, 1, 4, true><<<N_NODES / 64, 256, 0, stream>>>(P1, W1t, b1, P2);

    // layer 2: agg(H=256) then MFMA gemm + bias + tanh -> 256
    k_agg<256, false><<<N_NODES / 4, 256, 0, stream>>>(P2, P0, rowptr, col, dinv, nullptr);
    k_gemm_mfma<256, 256, 1, 4, true><<<N_NODES / 64, 256, 0, stream>>>(P0, W2t, b2, P1);

    // layer 3: MFMA gemm (no epilogue) -> 128, then agg + bias + tanh
    k_gemm_mfma<256, 128, 2, 2, false><<<N_NODES / 128, 256, 0, stream>>>(P1, W3t, nullptr, P2);
    k_agg<128, true><<<N_NODES / 4, 256, 0, stream>>>(P2, P0, rowptr, col, dinv, b3);

    // final FC: split-K partials + reduce
    k_fc<<<FC_SPLIT, 256, 0, stream>>>(P0, Wfc, fcpart);
    k_fc_reduce<<<NG * NOUT / 256, 256, 0, stream>>>(fcpart, bfc, out);
}

// Round 5
// 511.717 us; speedup vs baseline: 2.0190x; 1.0986x over previous
//
#include <hip/hip_runtime.h>
#include <math.h>

#define N_NODES 64000
#define N_EDGES 1048576
#define NB 1000
#define NG 64
#define NOUT 64
#define SCAN_BLOCKS 250   // 250 x 256 = 64000
#define FC_SPLIT 500      // 500 x 256 = 128000 K-rows

typedef __attribute__((ext_vector_type(8))) short bfrag;   // 8 bf16 = 4 VGPRs
typedef __attribute__((ext_vector_type(4))) float f32x4;

__device__ inline float bf2f(unsigned short u) {
    union { unsigned int i; float f; } x; x.i = ((unsigned int)u) << 16; return x.f;
}
__device__ inline unsigned short f2bf(float f) {   // round-to-nearest-even
    union { float f; unsigned int i; } x; x.f = f;
    return (unsigned short)((x.i + 0x7FFFu + ((x.i >> 16) & 1u)) >> 16);
}

// ---------------- CSR build ----------------

__global__ void k_count(const int* __restrict__ dst, int* __restrict__ indeg) {
    int e = blockIdx.x * blockDim.x + threadIdx.x;
    if (e < N_EDGES) atomicAdd(&indeg[dst[e]], 1);
}

__global__ void k_scan1(const int* __restrict__ indeg, int* __restrict__ local,
                        int* __restrict__ blocksum, float* __restrict__ dinv) {
    __shared__ int tmp[256];
    int t = threadIdx.x;
    int g = blockIdx.x * 256 + t;
    int v = indeg[g];
    dinv[g] = rsqrtf((float)(v + 1));       // +1 self loop
    tmp[t] = v;
    __syncthreads();
    for (int off = 1; off < 256; off <<= 1) {
        int o = (t >= off) ? tmp[t - off] : 0;
        __syncthreads();
        tmp[t] += o;
        __syncthreads();
    }
    local[g] = tmp[t] - v;
    if (t == 255) blocksum[blockIdx.x] = tmp[255];
}

__global__ void k_scan2(int* __restrict__ blocksum) {
    __shared__ int tmp[256];
    int t = threadIdx.x;
    int v = (t < SCAN_BLOCKS) ? blocksum[t] : 0;
    tmp[t] = v;
    __syncthreads();
    for (int off = 1; off < 256; off <<= 1) {
        int o = (t >= off) ? tmp[t - off] : 0;
        __syncthreads();
        tmp[t] += o;
        __syncthreads();
    }
    if (t < SCAN_BLOCKS) blocksum[t] = tmp[t] - v;
}

__global__ void k_scan3(const int* __restrict__ local, const int* __restrict__ blocksum,
                        int* __restrict__ rowptr, int* __restrict__ cursor) {
    int g = blockIdx.x * 256 + threadIdx.x;
    int r = local[g] + blocksum[blockIdx.x];
    rowptr[g] = r;
    cursor[g] = r;
    if (g == 0) rowptr[N_NODES] = N_EDGES;
}

__global__ void k_fill(const int* __restrict__ src, const int* __restrict__ dst,
                       int* __restrict__ cursor, int* __restrict__ col) {
    int e = blockIdx.x * blockDim.x + threadIdx.x;
    if (e < N_EDGES) {
        int d = dst[e];
        int p = atomicAdd(&cursor[d], 1);
        col[p] = src[e];
    }
}

// ---------------- casts ----------------

// fp32 -> bf16 with per-row dinv pre-scale (row = i/128)
__global__ void k_cast_scale(const float* __restrict__ in, const float* __restrict__ dinv,
                             unsigned short* __restrict__ out) {
    int i = (blockIdx.x * blockDim.x + threadIdx.x) * 4;
    float d = dinv[i >> 7];
    float4 v = *(const float4*)(in + i);
    union { unsigned short s[4]; uint2 u; } o;
    o.s[0] = f2bf(v.x * d); o.s[1] = f2bf(v.y * d);
    o.s[2] = f2bf(v.z * d); o.s[3] = f2bf(v.w * d);
    *(uint2*)(out + i) = o.u;
}

// W[K][N] fp32 -> Wt[N][K] bf16
__global__ void k_wt(const float* __restrict__ W, unsigned short* __restrict__ Wt,
                     int K, int N) {
    int i = blockIdx.x * 256 + threadIdx.x;
    if (i < K * N) {
        int n = i / K, k = i % K;
        Wt[i] = f2bf(W[k * N + n]);
    }
}

// ---------------- pull aggregation (bf16 in / bf16 out, fp32 math) ----------------
// inputs pre-scaled by dinv[u]:  agg[v] = dinv[v] * sum_{u in N(v) U {v}} hs[u]
// XCD swizzle: graph g's 250 blocks have blockIdx%8 == g%8 -> one graph per XCD
// at a time under round-robin dispatch; 512KB slab stays L2-resident.

template <int H, bool TANH>
__global__ void k_agg(const unsigned short* __restrict__ hs, unsigned short* __restrict__ op,
                      const int* __restrict__ rowptr, const int* __restrict__ col,
                      const float* __restrict__ dinv, const float* __restrict__ bias) {
    constexpr int VEC = H / 64;  // 2 (H=128) or 4 (H=256) bf16 per lane
    int lane = threadIdx.x & 63;
    int b = blockIdx.x;
    int c = b & 7;                 // target XCD
    int j = b >> 3;                // 0..1999
    int g = c + 8 * (j / 250);     // graph id
    int chunk = j % 250;
    int v = g * NB + chunk * 4 + (threadIdx.x >> 6);
    float acc[VEC];
    {   // self row (pre-scaled by dinv[v] already)
        const unsigned short* r = hs + (size_t)v * H + lane * VEC;
        if (VEC == 2) {
            unsigned int u = *(const unsigned int*)r;
            acc[0] = bf2f((unsigned short)(u & 0xffff));
            acc[1] = bf2f((unsigned short)(u >> 16));
        } else {
            uint2 u = *(const uint2*)r;
            acc[0] = bf2f((unsigned short)(u.x & 0xffff));
            acc[1] = bf2f((unsigned short)(u.x >> 16));
            acc[2] = bf2f((unsigned short)(u.y & 0xffff));
            acc[3] = bf2f((unsigned short)(u.y >> 16));
        }
    }
    int beg = rowptr[v], end = rowptr[v + 1];
    for (int e0 = beg; e0 < end; e0 += 64) {
        int me = e0 + lane;
        int s = (me < end) ? col[me] : 0;
        int cnt = min(64, end - e0);
        for (int i = 0; i < cnt; ++i) {
            int ss = __shfl(s, i);
            const unsigned short* r = hs + (size_t)ss * H + lane * VEC;
            if (VEC == 2) {
                unsigned int u = *(const unsigned int*)r;
                acc[0] += bf2f((unsigned short)(u & 0xffff));
                acc[1] += bf2f((unsigned short)(u >> 16));
            } else {
                uint2 u = *(const uint2*)r;
                acc[0] += bf2f((unsigned short)(u.x & 0xffff));
                acc[1] += bf2f((unsigned short)(u.x >> 16));
                acc[2] += bf2f((unsigned short)(u.y & 0xffff));
                acc[3] += bf2f((unsigned short)(u.y >> 16));
            }
        }
    }
    float dv = dinv[v];
    if (TANH) {
#pragma unroll
        for (int q = 0; q < VEC; ++q) acc[q] = tanhf(acc[q] * dv + bias[lane * VEC + q]);
    } else {
#pragma unroll
        for (int q = 0; q < VEC; ++q) acc[q] *= dv;
    }
    unsigned short* o = op + (size_t)v * H + lane * VEC;
    if (VEC == 2) {
        union { unsigned short s[2]; unsigned int u; } pk;
        pk.s[0] = f2bf(acc[0]); pk.s[1] = f2bf(acc[1]);
        *(unsigned int*)o = pk.u;
    } else {
        union { unsigned short s[4]; uint2 u; } pk;
        pk.s[0] = f2bf(acc[0]); pk.s[1] = f2bf(acc[1]);
        pk.s[2] = f2bf(acc[2]); pk.s[3] = f2bf(acc[3]);
        *(uint2*)o = pk.u;
    }
}

// ---------------- bf16 MFMA GEMM: C[M,N] = A[M,K] @ W[K,N], Wt pre-transposed [N][K]
// 4 waves, each 64x64 of 16x16x32 tiles, no LDS. Epilogue: optional bias+tanh (TB)
// and optional per-row dinv pre-scale for the next agg (SC).

template <int K, int N, int WM, int WN, bool TB, bool SC>
__global__ __launch_bounds__(256) void k_gemm_mfma(const unsigned short* __restrict__ A,
                                                   const unsigned short* __restrict__ Wt,
                                                   const float* __restrict__ bias,
                                                   const float* __restrict__ dinv,
                                                   unsigned short* __restrict__ C) {
    int w = threadIdx.x >> 6, l = threadIdx.x & 63;
    int lm = l & 15, lq = l >> 4;
    int wm = w / WN, wn = w % WN;
    int m0 = blockIdx.x * (WM * 64) + wm * 64;
    int n0 = wn * 64;
    f32x4 acc[4][4] = {};
    const unsigned short* Ab = A + (size_t)(m0 + lm) * K + lq * 8;
    const unsigned short* Bb = Wt + (size_t)(n0 + lm) * K + lq * 8;
#pragma unroll 2
    for (int ks = 0; ks < K; ks += 32) {
        bfrag af[4], bf[4];
#pragma unroll
        for (int i = 0; i < 4; ++i) af[i] = *(const bfrag*)(Ab + (size_t)i * 16 * K + ks);
#pragma unroll
        for (int j = 0; j < 4; ++j) bf[j] = *(const bfrag*)(Bb + (size_t)j * 16 * K + ks);
#pragma unroll
        for (int i = 0; i < 4; ++i)
#pragma unroll
            for (int j = 0; j < 4; ++j)
                acc[i][j] = __builtin_amdgcn_mfma_f32_16x16x32_bf16(af[i], bf[j], acc[i][j], 0, 0, 0);
    }
    float bj[4];
    if (TB) {
#pragma unroll
        for (int j = 0; j < 4; ++j) bj[j] = bias[n0 + j * 16 + lm];
    }
    int row0 = lq * 4;
    float drow[4][4];
    if (SC) {
#pragma unroll
        for (int i = 0; i < 4; ++i)
#pragma unroll
            for (int r = 0; r < 4; ++r) drow[i][r] = dinv[m0 + i * 16 + row0 + r];
    }
#pragma unroll
    for (int i = 0; i < 4; ++i)
#pragma unroll
        for (int j = 0; j < 4; ++j) {
#pragma unroll
            for (int r = 0; r < 4; ++r) {
                float v = acc[i][j][r];
                if (TB) v = tanhf(v + bj[j]);
                if (SC) v *= drow[i][r];
                C[(size_t)(m0 + i * 16 + row0 + r) * N + n0 + j * 16 + lm] = f2bf(v);
            }
        }
}

// ---------------- final FC: out[64,64] = h[64,128000](bf16) @ Wfc[128000,64](f32) + bfc

__global__ void k_fc(const unsigned short* __restrict__ A, const float* __restrict__ B,
                     float* __restrict__ part) {
    __shared__ float As[16][68];
    __shared__ float Bs[16][68];
    const int KROW = NB * 128;         // 128000
    int t = threadIdx.x;
    int tx = t & 15, ty = t >> 4;
    int k0b = blockIdx.x * 256;
    float acc[4][4] = {};
    for (int k0 = k0b; k0 < k0b + 256; k0 += 16) {
        int arow = t >> 2, ak = (t & 3) << 2;
        uint2 ua = *(const uint2*)(A + (size_t)arow * KROW + k0 + ak);
        As[ak + 0][arow] = bf2f((unsigned short)(ua.x & 0xffff));
        As[ak + 1][arow] = bf2f((unsigned short)(ua.x >> 16));
        As[ak + 2][arow] = bf2f((unsigned short)(ua.y & 0xffff));
        As[ak + 3][arow] = bf2f((unsigned short)(ua.y >> 16));
        int bk = t >> 4, bn4 = (t & 15) << 2;
        *(float4*)&Bs[bk][bn4] = *(const float4*)(B + (size_t)(k0 + bk) * NOUT + bn4);
        __syncthreads();
#pragma unroll
        for (int kk = 0; kk < 16; ++kk) {
            float4 a = *(const float4*)&As[kk][ty << 2];
            float4 b = *(const float4*)&Bs[kk][tx << 2];
            acc[0][0] += a.x * b.x; acc[0][1] += a.x * b.y; acc[0][2] += a.x * b.z; acc[0][3] += a.x * b.w;
            acc[1][0] += a.y * b.x; acc[1][1] += a.y * b.y; acc[1][2] += a.y * b.z; acc[1][3] += a.y * b.w;
            acc[2][0] += a.z * b.x; acc[2][1] += a.z * b.y; acc[2][2] += a.z * b.z; acc[2][3] += a.z * b.w;
            acc[3][0] += a.w * b.x; acc[3][1] += a.w * b.y; acc[3][2] += a.w * b.z; acc[3][3] += a.w * b.w;
        }
        __syncthreads();
    }
    float* po = part + (size_t)blockIdx.x * (NG * NOUT);
#pragma unroll
    for (int i = 0; i < 4; ++i) {
        float4 r;
        r.x = acc[i][0]; r.y = acc[i][1]; r.z = acc[i][2]; r.w = acc[i][3];
        *(float4*)&po[((ty << 2) + i) * NOUT + (tx << 2)] = r;
    }
}

__global__ void k_fc_reduce(const float* __restrict__ part, const float* __restrict__ bfc,
                            float* __restrict__ out) {
    int i = blockIdx.x * blockDim.x + threadIdx.x;   // 4096 threads
    float s = bfc[i & 63];
    for (int b = 0; b < FC_SPLIT; ++b) s += part[(size_t)b * (NG * NOUT) + i];
    out[i] = s;
}

// ---------------- driver ----------------

static inline size_t align256(size_t x) { return (x + 255) & ~(size_t)255; }

extern "C" void kernel_launch(void* const* d_in, const int* in_sizes, int n_in,
                              void* d_out, int out_size, void* d_ws, size_t ws_size,
                              hipStream_t stream) {
    const float* x   = (const float*)d_in[0];
    const int*   ei  = (const int*)d_in[1];
    const int*   src = ei;
    const int*   dst = ei + N_EDGES;
    const float* W1  = (const float*)d_in[3];
    const float* b1  = (const float*)d_in[4];
    const float* W2  = (const float*)d_in[5];
    const float* b2  = (const float*)d_in[6];
    const float* W3  = (const float*)d_in[7];
    const float* b3  = (const float*)d_in[8];
    const float* Wfc = (const float*)d_in[9];
    const float* bfc = (const float*)d_in[10];
    float* out = (float*)d_out;

    char* w = (char*)d_ws;
    unsigned short* P0 = (unsigned short*)w; w += align256((size_t)N_NODES * 256 * 2);
    unsigned short* P1 = (unsigned short*)w; w += align256((size_t)N_NODES * 256 * 2);
    unsigned short* P2 = (unsigned short*)w; w += align256((size_t)N_NODES * 256 * 2);
    int* indeg = (int*)w;       w += align256((size_t)N_NODES * 4);
    int* rowptr = (int*)w;      w += align256((size_t)(N_NODES + 1) * 4);
    int* cursor = (int*)w;      w += align256((size_t)N_NODES * 4);
    float* dinv = (float*)w;    w += align256((size_t)N_NODES * 4);
    int* col = (int*)w;         w += align256((size_t)N_EDGES * 4);
    int* slocal = (int*)w;      w += align256((size_t)N_NODES * 4);
    int* sblock = (int*)w;      w += align256((size_t)SCAN_BLOCKS * 4);
    float* fcpart = (float*)w;  w += align256((size_t)FC_SPLIT * NG * NOUT * 4);
    unsigned short* W1t = (unsigned short*)w; w += align256((size_t)128 * 256 * 2);
    unsigned short* W2t = (unsigned short*)w; w += align256((size_t)256 * 256 * 2);
    unsigned short* W3t = (unsigned short*)w; w += align256((size_t)256 * 128 * 2);

    // CSR build
    hipMemsetAsync(indeg, 0, (size_t)N_NODES * 4, stream);
    k_count<<<N_EDGES / 256, 256, 0, stream>>>(dst, indeg);
    k_scan1<<<SCAN_BLOCKS, 256, 0, stream>>>(indeg, slocal, sblock, dinv);
    k_scan2<<<1, 256, 0, stream>>>(sblock);
    k_scan3<<<SCAN_BLOCKS, 256, 0, stream>>>(slocal, sblock, rowptr, cursor);
    k_fill<<<N_EDGES / 256, 256, 0, stream>>>(src, dst, cursor, col);

    // casts: x -> bf16 pre-scaled by dinv (P0); weights -> transposed bf16
    k_cast_scale<<<(N_NODES * 128 / 4) / 256, 256, 0, stream>>>(x, dinv, P0);
    k_wt<<<(128 * 256 + 255) / 256, 256, 0, stream>>>(W1, W1t, 128, 256);
    k_wt<<<(256 * 256 + 255) / 256, 256, 0, stream>>>(W2, W2t, 256, 256);
    k_wt<<<(256 * 128 + 255) / 256, 256, 0, stream>>>(W3, W3t, 256, 128);

    // layer 1: agg(H=128), gemm+bias+tanh+prescale -> 256
    k_agg<128, false><<<N_NODES / 4, 256, 0, stream>>>(P0, P1, rowptr, col, dinv, nullptr);
    k_gemm_mfma<128, 256, 1, 4, true, true><<<N_NODES / 64, 256, 0, stream>>>(P1, W1t, b1, dinv, P2);

    // layer 2: agg(H=256), gemm+bias+tanh (no prescale: feeds gemm3) -> 256
    k_agg<256, false><<<N_NODES / 4, 256, 0, stream>>>(P2, P0, rowptr, col, dinv, nullptr);
    k_gemm_mfma<256, 256, 1, 4, true, false><<<N_NODES / 64, 256, 0, stream>>>(P0, W2t, b2, dinv, P1);

    // layer 3: gemm (no bias/tanh) + prescale -> 128, then agg + bias + tanh
    k_gemm_mfma<256, 128, 2, 2, false, true><<<N_NODES / 128, 256, 0, stream>>>(P1, W3t, nullptr, dinv, P2);
    k_agg<128, true><<<N_NODES / 4, 256, 0, stream>>>(P2, P0, rowptr, col, dinv, b3);

    // final FC: split-K partials + reduce
    k_fc<<<FC_SPLIT, 256, 0, stream>>>(P0, Wfc, fcpart);
    k_fc_reduce<<<NG * NOUT / 256, 256, 0, stream>>>(fcpart, bfc, out);
}

// Round 6
// 442.828 us; speedup vs baseline: 2.3331x; 1.1556x over previous
//
#include <hip/hip_runtime.h>
#include <math.h>

#define N_NODES 64000
#define N_EDGES 1048576
#define NB 1000
#define NG 64
#define NOUT 64
#define FC_SPLIT 500      // 500 x 256 = 128000 K-rows
#define BK_CAP 18000      // per-graph edge bucket capacity (mean 16384, +12.7 sigma)

typedef __attribute__((ext_vector_type(8))) short bfrag;   // 8 bf16 = 4 VGPRs
typedef __attribute__((ext_vector_type(4))) float f32x4;

__device__ inline float bf2f(unsigned short u) {
    union { unsigned int i; float f; } x; x.i = ((unsigned int)u) << 16; return x.f;
}
__device__ inline unsigned short f2bf(float f) {   // round-to-nearest-even
    union { float f; unsigned int i; } x; x.f = f;
    return (unsigned short)((x.i + 0x7FFFu + ((x.i >> 16) & 1u)) >> 16);
}

// ---------------- CSR build, graph-bucketed ----------------
// Phase A: partition edges into 64 per-graph buckets, packed (dl<<10)|sl.
// LDS histogram -> one global atomic per (block,bucket) -> near-contiguous writes.

__global__ __launch_bounds__(256) void k_bucket(const int* __restrict__ src,
                                                const int* __restrict__ dst,
                                                int* __restrict__ gcnt,
                                                unsigned int* __restrict__ bucket) {
    __shared__ int lcnt[64];
    __shared__ int lbase[64];
    __shared__ int lcur[64];
    int t = threadIdx.x;
    int e0 = blockIdx.x * 4096;
    if (t < 64) { lcnt[t] = 0; lcur[t] = 0; }
    __syncthreads();
    for (int i = t; i < 4096; i += 256) {
        int d = dst[e0 + i];
        int g = d / NB;
        atomicAdd(&lcnt[g], 1);
    }
    __syncthreads();
    if (t < 64) lbase[t] = atomicAdd(&gcnt[t], lcnt[t]);
    __syncthreads();
    for (int i = t; i < 4096; i += 256) {
        int d = dst[e0 + i];
        int s = src[e0 + i];
        int g = d / NB;
        int pos = atomicAdd(&lcur[g], 1);
        unsigned int packed = ((unsigned int)(d - g * NB) << 10) | (unsigned int)(s - g * NB);
        bucket[(size_t)g * BK_CAP + lbase[g] + pos] = packed;
    }
}

// Phase B: one block per graph. LDS indeg + scan -> rowptr/rowend/dinv, scatter
// ushort local src ids into the graph's private col region (L2-local).

__global__ __launch_bounds__(1024) void k_build(const int* __restrict__ gcnt,
                                                const unsigned int* __restrict__ bucket,
                                                int* __restrict__ rowptr,
                                                int* __restrict__ rowend,
                                                float* __restrict__ dinv,
                                                unsigned short* __restrict__ colp) {
    __shared__ int ind[1024];
    __shared__ int tmp[1024];
    int t = threadIdx.x;
    int g = blockIdx.x;
    int cnt = gcnt[g];
    size_t base = (size_t)g * BK_CAP;
    ind[t] = 0;
    __syncthreads();
    for (int i = t; i < cnt; i += 1024) {
        unsigned int p = bucket[base + i];
        atomicAdd(&ind[p >> 10], 1);
    }
    __syncthreads();
    int deg = ind[t];
    if (t < NB) dinv[g * NB + t] = rsqrtf((float)(deg + 1));
    tmp[t] = deg;
    __syncthreads();
    for (int off = 1; off < 1024; off <<= 1) {
        int o = (t >= off) ? tmp[t - off] : 0;
        __syncthreads();
        tmp[t] += o;
        __syncthreads();
    }
    int excl = tmp[t] - deg;
    if (t < NB) {
        rowptr[g * NB + t] = (int)base + excl;
        rowend[g * NB + t] = (int)base + excl + deg;
    }
    ind[t] = excl;           // reuse as cursor
    __syncthreads();
    for (int i = t; i < cnt; i += 1024) {
        unsigned int p = bucket[base + i];
        int dl = p >> 10;
        int pos = atomicAdd(&ind[dl], 1);
        colp[base + pos] = (unsigned short)(p & 1023u);
    }
}

// ---------------- casts ----------------

// fp32 -> bf16 with per-row dinv pre-scale (row = i/128)
__global__ void k_cast_scale(const float* __restrict__ in, const float* __restrict__ dinv,
                             unsigned short* __restrict__ out) {
    int i = (blockIdx.x * blockDim.x + threadIdx.x) * 4;
    float d = dinv[i >> 7];
    float4 v = *(const float4*)(in + i);
    union { unsigned short s[4]; uint2 u; } o;
    o.s[0] = f2bf(v.x * d); o.s[1] = f2bf(v.y * d);
    o.s[2] = f2bf(v.z * d); o.s[3] = f2bf(v.w * d);
    *(uint2*)(out + i) = o.u;
}

// W[K][N] fp32 -> Wt[N][K] bf16
__global__ void k_wt(const float* __restrict__ W, unsigned short* __restrict__ Wt,
                     int K, int N) {
    int i = blockIdx.x * 256 + threadIdx.x;
    if (i < K * N) {
        int n = i / K, k = i % K;
        Wt[i] = f2bf(W[k * N + n]);
    }
}

// ---------------- pull aggregation (bf16 in / bf16 out, fp32 math) ----------------
// inputs pre-scaled by dinv[u]:  agg[v] = dinv[v] * sum_{u in N(v) U {v}} hs[u]
// col holds ushort LOCAL ids; src global = g*NB + local (g known per block).
// XCD swizzle: graph g's blocks have blockIdx%8 == g%8.

template <int H, bool TANH>
__global__ void k_agg(const unsigned short* __restrict__ hs, unsigned short* __restrict__ op,
                      const int* __restrict__ rowptr, const int* __restrict__ rowend,
                      const unsigned short* __restrict__ col,
                      const float* __restrict__ dinv, const float* __restrict__ bias) {
    constexpr int VEC = H / 64;  // 2 (H=128) or 4 (H=256) bf16 per lane
    int lane = threadIdx.x & 63;
    int b = blockIdx.x;
    int c = b & 7;                 // target XCD
    int j = b >> 3;                // 0..1999
    int g = c + 8 * (j / 250);     // graph id
    int chunk = j % 250;
    int v = g * NB + chunk * 4 + (threadIdx.x >> 6);
    const unsigned short* gb = hs + (size_t)g * NB * H;   // graph feature slab
    float acc[VEC];
    {   // self row (pre-scaled by dinv[v] already)
        const unsigned short* r = hs + (size_t)v * H + lane * VEC;
        if (VEC == 2) {
            unsigned int u = *(const unsigned int*)r;
            acc[0] = bf2f((unsigned short)(u & 0xffff));
            acc[1] = bf2f((unsigned short)(u >> 16));
        } else {
            uint2 u = *(const uint2*)r;
            acc[0] = bf2f((unsigned short)(u.x & 0xffff));
            acc[1] = bf2f((unsigned short)(u.x >> 16));
            acc[2] = bf2f((unsigned short)(u.y & 0xffff));
            acc[3] = bf2f((unsigned short)(u.y >> 16));
        }
    }
    int beg = rowptr[v], end = rowend[v];
    for (int e0 = beg; e0 < end; e0 += 64) {
        int me = e0 + lane;
        int s = (me < end) ? (int)col[me] : 0;
        int cnt = min(64, end - e0);
        for (int i = 0; i < cnt; ++i) {
            int ss = __shfl(s, i);
            const unsigned short* r = gb + (size_t)ss * H + lane * VEC;
            if (VEC == 2) {
                unsigned int u = *(const unsigned int*)r;
                acc[0] += bf2f((unsigned short)(u & 0xffff));
                acc[1] += bf2f((unsigned short)(u >> 16));
            } else {
                uint2 u = *(const uint2*)r;
                acc[0] += bf2f((unsigned short)(u.x & 0xffff));
                acc[1] += bf2f((unsigned short)(u.x >> 16));
                acc[2] += bf2f((unsigned short)(u.y & 0xffff));
                acc[3] += bf2f((unsigned short)(u.y >> 16));
            }
        }
    }
    float dv = dinv[v];
    if (TANH) {
#pragma unroll
        for (int q = 0; q < VEC; ++q) acc[q] = tanhf(acc[q] * dv + bias[lane * VEC + q]);
    } else {
#pragma unroll
        for (int q = 0; q < VEC; ++q) acc[q] *= dv;
    }
    unsigned short* o = op + (size_t)v * H + lane * VEC;
    if (VEC == 2) {
        union { unsigned short s[2]; unsigned int u; } pk;
        pk.s[0] = f2bf(acc[0]); pk.s[1] = f2bf(acc[1]);
        *(unsigned int*)o = pk.u;
    } else {
        union { unsigned short s[4]; uint2 u; } pk;
        pk.s[0] = f2bf(acc[0]); pk.s[1] = f2bf(acc[1]);
        pk.s[2] = f2bf(acc[2]); pk.s[3] = f2bf(acc[3]);
        *(uint2*)o = pk.u;
    }
}

// ---------------- bf16 MFMA GEMM: C[M,N] = A[M,K] @ W[K,N], Wt pre-transposed [N][K]
// 4 waves, each 64x64 of 16x16x32 tiles, no LDS. Epilogue: optional bias+tanh (TB)
// and optional per-row dinv pre-scale for the next agg (SC).

template <int K, int N, int WM, int WN, bool TB, bool SC>
__global__ __launch_bounds__(256) void k_gemm_mfma(const unsigned short* __restrict__ A,
                                                   const unsigned short* __restrict__ Wt,
                                                   const float* __restrict__ bias,
                                                   const float* __restrict__ dinv,
                                                   unsigned short* __restrict__ C) {
    int w = threadIdx.x >> 6, l = threadIdx.x & 63;
    int lm = l & 15, lq = l >> 4;
    int wm = w / WN, wn = w % WN;
    int m0 = blockIdx.x * (WM * 64) + wm * 64;
    int n0 = wn * 64;
    f32x4 acc[4][4] = {};
    const unsigned short* Ab = A + (size_t)(m0 + lm) * K + lq * 8;
    const unsigned short* Bb = Wt + (size_t)(n0 + lm) * K + lq * 8;
#pragma unroll 2
    for (int ks = 0; ks < K; ks += 32) {
        bfrag af[4], bf[4];
#pragma unroll
        for (int i = 0; i < 4; ++i) af[i] = *(const bfrag*)(Ab + (size_t)i * 16 * K + ks);
#pragma unroll
        for (int j = 0; j < 4; ++j) bf[j] = *(const bfrag*)(Bb + (size_t)j * 16 * K + ks);
#pragma unroll
        for (int i = 0; i < 4; ++i)
#pragma unroll
            for (int j = 0; j < 4; ++j)
                acc[i][j] = __builtin_amdgcn_mfma_f32_16x16x32_bf16(af[i], bf[j], acc[i][j], 0, 0, 0);
    }
    float bj[4];
    if (TB) {
#pragma unroll
        for (int j = 0; j < 4; ++j) bj[j] = bias[n0 + j * 16 + lm];
    }
    int row0 = lq * 4;
    float drow[4][4];
    if (SC) {
#pragma unroll
        for (int i = 0; i < 4; ++i)
#pragma unroll
            for (int r = 0; r < 4; ++r) drow[i][r] = dinv[m0 + i * 16 + row0 + r];
    }
#pragma unroll
    for (int i = 0; i < 4; ++i)
#pragma unroll
        for (int j = 0; j < 4; ++j) {
#pragma unroll
            for (int r = 0; r < 4; ++r) {
                float v = acc[i][j][r];
                if (TB) v = tanhf(v + bj[j]);
                if (SC) v *= drow[i][r];
                C[(size_t)(m0 + i * 16 + row0 + r) * N + n0 + j * 16 + lm] = f2bf(v);
            }
        }
}

// ---------------- final FC: out[64,64] = h[64,128000](bf16) @ Wfc[128000,64](f32) + bfc

__global__ void k_fc(const unsigned short* __restrict__ A, const float* __restrict__ B,
                     float* __restrict__ part) {
    __shared__ float As[16][68];
    __shared__ float Bs[16][68];
    const int KROW = NB * 128;         // 128000
    int t = threadIdx.x;
    int tx = t & 15, ty = t >> 4;
    int k0b = blockIdx.x * 256;
    float acc[4][4] = {};
    for (int k0 = k0b; k0 < k0b + 256; k0 += 16) {
        int arow = t >> 2, ak = (t & 3) << 2;
        uint2 ua = *(const uint2*)(A + (size_t)arow * KROW + k0 + ak);
        As[ak + 0][arow] = bf2f((unsigned short)(ua.x & 0xffff));
        As[ak + 1][arow] = bf2f((unsigned short)(ua.x >> 16));
        As[ak + 2][arow] = bf2f((unsigned short)(ua.y & 0xffff));
        As[ak + 3][arow] = bf2f((unsigned short)(ua.y >> 16));
        int bk = t >> 4, bn4 = (t & 15) << 2;
        *(float4*)&Bs[bk][bn4] = *(const float4*)(B + (size_t)(k0 + bk) * NOUT + bn4);
        __syncthreads();
#pragma unroll
        for (int kk = 0; kk < 16; ++kk) {
            float4 a = *(const float4*)&As[kk][ty << 2];
            float4 b = *(const float4*)&Bs[kk][tx << 2];
            acc[0][0] += a.x * b.x; acc[0][1] += a.x * b.y; acc[0][2] += a.x * b.z; acc[0][3] += a.x * b.w;
            acc[1][0] += a.y * b.x; acc[1][1] += a.y * b.y; acc[1][2] += a.y * b.z; acc[1][3] += a.y * b.w;
            acc[2][0] += a.z * b.x; acc[2][1] += a.z * b.y; acc[2][2] += a.z * b.z; acc[2][3] += a.z * b.w;
            acc[3][0] += a.w * b.x; acc[3][1] += a.w * b.y; acc[3][2] += a.w * b.z; acc[3][3] += a.w * b.w;
        }
        __syncthreads();
    }
    float* po = part + (size_t)blockIdx.x * (NG * NOUT);
#pragma unroll
    for (int i = 0; i < 4; ++i) {
        float4 r;
        r.x = acc[i][0]; r.y = acc[i][1]; r.z = acc[i][2]; r.w = acc[i][3];
        *(float4*)&po[((ty << 2) + i) * NOUT + (tx << 2)] = r;
    }
}

__global__ void k_fc_reduce(const float* __restrict__ part, const float* __restrict__ bfc,
                            float* __restrict__ out) {
    int i = blockIdx.x * blockDim.x + threadIdx.x;   // 4096 threads
    float s = bfc[i & 63];
    for (int b = 0; b < FC_SPLIT; ++b) s += part[(size_t)b * (NG * NOUT) + i];
    out[i] = s;
}

// ---------------- driver ----------------

static inline size_t align256(size_t x) { return (x + 255) & ~(size_t)255; }

extern "C" void kernel_launch(void* const* d_in, const int* in_sizes, int n_in,
                              void* d_out, int out_size, void* d_ws, size_t ws_size,
                              hipStream_t stream) {
    const float* x   = (const float*)d_in[0];
    const int*   ei  = (const int*)d_in[1];
    const int*   src = ei;
    const int*   dst = ei + N_EDGES;
    const float* W1  = (const float*)d_in[3];
    const float* b1  = (const float*)d_in[4];
    const float* W2  = (const float*)d_in[5];
    const float* b2  = (const float*)d_in[6];
    const float* W3  = (const float*)d_in[7];
    const float* b3  = (const float*)d_in[8];
    const float* Wfc = (const float*)d_in[9];
    const float* bfc = (const float*)d_in[10];
    float* out = (float*)d_out;

    char* w = (char*)d_ws;
    unsigned short* P0 = (unsigned short*)w; w += align256((size_t)N_NODES * 256 * 2);
    unsigned short* P1 = (unsigned short*)w; w += align256((size_t)N_NODES * 256 * 2);
    unsigned short* P2 = (unsigned short*)w; w += align256((size_t)N_NODES * 256 * 2);
    int* rowptr = (int*)w;      w += align256((size_t)N_NODES * 4);
    int* rowend = (int*)w;      w += align256((size_t)N_NODES * 4);
    float* dinv = (float*)w;    w += align256((size_t)N_NODES * 4);
    int* gcnt = (int*)w;        w += align256((size_t)NG * 4);
    unsigned int* bucket = (unsigned int*)w; w += align256((size_t)NG * BK_CAP * 4);
    unsigned short* colp = (unsigned short*)w; w += align256((size_t)NG * BK_CAP * 2);
    float* fcpart = (float*)w;  w += align256((size_t)FC_SPLIT * NG * NOUT * 4);
    unsigned short* W1t = (unsigned short*)w; w += align256((size_t)128 * 256 * 2);
    unsigned short* W2t = (unsigned short*)w; w += align256((size_t)256 * 256 * 2);
    unsigned short* W3t = (unsigned short*)w; w += align256((size_t)256 * 128 * 2);

    // CSR build: bucket by graph, then per-graph local build (no global scatter)
    hipMemsetAsync(gcnt, 0, (size_t)NG * 4, stream);
    k_bucket<<<N_EDGES / 4096, 256, 0, stream>>>(src, dst, gcnt, bucket);
    k_build<<<NG, 1024, 0, stream>>>(gcnt, bucket, rowptr, rowend, dinv, colp);

    // casts: x -> bf16 pre-scaled by dinv (P0); weights -> transposed bf16
    k_cast_scale<<<(N_NODES * 128 / 4) / 256, 256, 0, stream>>>(x, dinv, P0);
    k_wt<<<(128 * 256 + 255) / 256, 256, 0, stream>>>(W1, W1t, 128, 256);
    k_wt<<<(256 * 256 + 255) / 256, 256, 0, stream>>>(W2, W2t, 256, 256);
    k_wt<<<(256 * 128 + 255) / 256, 256, 0, stream>>>(W3, W3t, 256, 128);

    // layer 1: agg(H=128), gemm+bias+tanh+prescale -> 256
    k_agg<128, false><<<N_NODES / 4, 256, 0, stream>>>(P0, P1, rowptr, rowend, colp, dinv, nullptr);
    k_gemm_mfma<128, 256, 1, 4, true, true><<<N_NODES / 64, 256, 0, stream>>>(P1, W1t, b1, dinv, P2);

    // layer 2: agg(H=256), gemm+bias+tanh (no prescale: feeds gemm3) -> 256
    k_agg<256, false><<<N_NODES / 4, 256, 0, stream>>>(P2, P0, rowptr, rowend, colp, dinv, nullptr);
    k_gemm_mfma<256, 256, 1, 4, true, false><<<N_NODES / 64, 256, 0, stream>>>(P0, W2t, b2, dinv, P1);

    // layer 3: gemm (no bias/tanh) + prescale -> 128, then agg + bias + tanh
    k_gemm_mfma<256, 128, 2, 2, false, true><<<N_NODES / 128, 256, 0, stream>>>(P1, W3t, nullptr, dinv, P2);
    k_agg<128, true><<<N_NODES / 4, 256, 0, stream>>>(P2, P0, rowptr, rowend, colp, dinv, b3);

    // final FC: split-K partials + reduce
    k_fc<<<FC_SPLIT, 256, 0, stream>>>(P0, Wfc, fcpart);
    k_fc_reduce<<<NG * NOUT / 256, 256, 0, stream>>>(fcpart, bfc, out);
}

// Round 7
// 418.268 us; speedup vs baseline: 2.4701x; 1.0587x over previous
//
#include <hip/hip_runtime.h>
#include <math.h>

#define N_NODES 64000
#define N_EDGES 1048576
#define NB 1000
#define NG 64
#define NOUT 64
#define FC_SPLIT 500      // 500 x 256 = 128000 K-rows
#define BK_CAP 18000      // per-graph edge bucket capacity (mean 16384, +12.7 sigma)

typedef __attribute__((ext_vector_type(8))) short bfrag;   // 8 bf16 = 4 VGPRs
typedef __attribute__((ext_vector_type(4))) float f32x4;

__device__ inline float bf2f(unsigned short u) {
    union { unsigned int i; float f; } x; x.i = ((unsigned int)u) << 16; return x.f;
}
__device__ inline unsigned short f2bf(float f) {   // round-to-nearest-even
    union { float f; unsigned int i; } x; x.f = f;
    return (unsigned short)((x.i + 0x7FFFu + ((x.i >> 16) & 1u)) >> 16);
}

// ---------------- CSR build, graph-bucketed ----------------

__global__ __launch_bounds__(256) void k_bucket(const int* __restrict__ src,
                                                const int* __restrict__ dst,
                                                int* __restrict__ gcnt,
                                                unsigned int* __restrict__ bucket) {
    __shared__ int lcnt[64];
    __shared__ int lbase[64];
    __shared__ int lcur[64];
    int t = threadIdx.x;
    int e0 = blockIdx.x * 4096;
    if (t < 64) { lcnt[t] = 0; lcur[t] = 0; }
    __syncthreads();
    for (int i = t; i < 4096; i += 256) {
        int d = dst[e0 + i];
        int g = d / NB;
        atomicAdd(&lcnt[g], 1);
    }
    __syncthreads();
    if (t < 64) lbase[t] = atomicAdd(&gcnt[t], lcnt[t]);
    __syncthreads();
    for (int i = t; i < 4096; i += 256) {
        int d = dst[e0 + i];
        int s = src[e0 + i];
        int g = d / NB;
        int pos = atomicAdd(&lcur[g], 1);
        unsigned int packed = ((unsigned int)(d - g * NB) << 10) | (unsigned int)(s - g * NB);
        bucket[(size_t)g * BK_CAP + lbase[g] + pos] = packed;
    }
}

__global__ __launch_bounds__(1024) void k_build(const int* __restrict__ gcnt,
                                                const unsigned int* __restrict__ bucket,
                                                int* __restrict__ rowptr,
                                                int* __restrict__ rowend,
                                                float* __restrict__ dinv,
                                                unsigned short* __restrict__ colp) {
    __shared__ int ind[1024];
    __shared__ int tmp[1024];
    int t = threadIdx.x;
    int g = blockIdx.x;
    int cnt = gcnt[g];
    size_t base = (size_t)g * BK_CAP;
    ind[t] = 0;
    __syncthreads();
    for (int i = t; i < cnt; i += 1024) {
        unsigned int p = bucket[base + i];
        atomicAdd(&ind[p >> 10], 1);
    }
    __syncthreads();
    int deg = ind[t];
    if (t < NB) dinv[g * NB + t] = rsqrtf((float)(deg + 1));
    tmp[t] = deg;
    __syncthreads();
    for (int off = 1; off < 1024; off <<= 1) {
        int o = (t >= off) ? tmp[t - off] : 0;
        __syncthreads();
        tmp[t] += o;
        __syncthreads();
    }
    int excl = tmp[t] - deg;
    if (t < NB) {
        rowptr[g * NB + t] = (int)base + excl;
        rowend[g * NB + t] = (int)base + excl + deg;
    }
    ind[t] = excl;           // reuse as cursor
    __syncthreads();
    for (int i = t; i < cnt; i += 1024) {
        unsigned int p = bucket[base + i];
        int dl = p >> 10;
        int pos = atomicAdd(&ind[dl], 1);
        colp[base + pos] = (unsigned short)(p & 1023u);
    }
}

// ---------------- casts ----------------

__global__ void k_cast_scale(const float* __restrict__ in, const float* __restrict__ dinv,
                             unsigned short* __restrict__ out) {
    int i = (blockIdx.x * blockDim.x + threadIdx.x) * 4;
    float d = dinv[i >> 7];
    float4 v = *(const float4*)(in + i);
    union { unsigned short s[4]; uint2 u; } o;
    o.s[0] = f2bf(v.x * d); o.s[1] = f2bf(v.y * d);
    o.s[2] = f2bf(v.z * d); o.s[3] = f2bf(v.w * d);
    *(uint2*)(out + i) = o.u;
}

// W[K][N] fp32 -> Wt[N][K] bf16
__global__ void k_wt(const float* __restrict__ W, unsigned short* __restrict__ Wt,
                     int K, int N) {
    int i = blockIdx.x * 256 + threadIdx.x;
    if (i < K * N) {
        int n = i / K, k = i % K;
        Wt[i] = f2bf(W[k * N + n]);
    }
}

// ---------------- pull aggregation (bf16 in / bf16 out, fp32 math) ----------------

template <int H, bool TANH>
__global__ void k_agg(const unsigned short* __restrict__ hs, unsigned short* __restrict__ op,
                      const int* __restrict__ rowptr, const int* __restrict__ rowend,
                      const unsigned short* __restrict__ col,
                      const float* __restrict__ dinv, const float* __restrict__ bias) {
    constexpr int VEC = H / 64;
    int lane = threadIdx.x & 63;
    int b = blockIdx.x;
    int c = b & 7;
    int j = b >> 3;
    int g = c + 8 * (j / 250);
    int chunk = j % 250;
    int v = g * NB + chunk * 4 + (threadIdx.x >> 6);
    const unsigned short* gb = hs + (size_t)g * NB * H;
    float acc[VEC];
    {
        const unsigned short* r = hs + (size_t)v * H + lane * VEC;
        if (VEC == 2) {
            unsigned int u = *(const unsigned int*)r;
            acc[0] = bf2f((unsigned short)(u & 0xffff));
            acc[1] = bf2f((unsigned short)(u >> 16));
        } else {
            uint2 u = *(const uint2*)r;
            acc[0] = bf2f((unsigned short)(u.x & 0xffff));
            acc[1] = bf2f((unsigned short)(u.x >> 16));
            acc[2] = bf2f((unsigned short)(u.y & 0xffff));
            acc[3] = bf2f((unsigned short)(u.y >> 16));
        }
    }
    int beg = rowptr[v], end = rowend[v];
    for (int e0 = beg; e0 < end; e0 += 64) {
        int me = e0 + lane;
        int s = (me < end) ? (int)col[me] : 0;
        int cnt = min(64, end - e0);
        for (int i = 0; i < cnt; ++i) {
            int ss = __shfl(s, i);
            const unsigned short* r = gb + (size_t)ss * H + lane * VEC;
            if (VEC == 2) {
                unsigned int u = *(const unsigned int*)r;
                acc[0] += bf2f((unsigned short)(u & 0xffff));
                acc[1] += bf2f((unsigned short)(u >> 16));
            } else {
                uint2 u = *(const uint2*)r;
                acc[0] += bf2f((unsigned short)(u.x & 0xffff));
                acc[1] += bf2f((unsigned short)(u.x >> 16));
                acc[2] += bf2f((unsigned short)(u.y & 0xffff));
                acc[3] += bf2f((unsigned short)(u.y >> 16));
            }
        }
    }
    float dv = dinv[v];
    if (TANH) {
#pragma unroll
        for (int q = 0; q < VEC; ++q) acc[q] = tanhf(acc[q] * dv + bias[lane * VEC + q]);
    } else {
#pragma unroll
        for (int q = 0; q < VEC; ++q) acc[q] *= dv;
    }
    unsigned short* o = op + (size_t)v * H + lane * VEC;
    if (VEC == 2) {
        union { unsigned short s[2]; unsigned int u; } pk;
        pk.s[0] = f2bf(acc[0]); pk.s[1] = f2bf(acc[1]);
        *(unsigned int*)o = pk.u;
    } else {
        union { unsigned short s[4]; uint2 u; } pk;
        pk.s[0] = f2bf(acc[0]); pk.s[1] = f2bf(acc[1]);
        pk.s[2] = f2bf(acc[2]); pk.s[3] = f2bf(acc[3]);
        *(uint2*)o = pk.u;
    }
}

// ---------------- layer-1 GEMM: C[64000,256] = tanh(A[64000,128] @ W1 + b1) * dinv
// 4 waves per block, wave = 64 rows x 64 cols, A-frag double-buffer prefetch.

__global__ __launch_bounds__(256) void k_gemm1(const unsigned short* __restrict__ A,
                                               const unsigned short* __restrict__ W1t,
                                               const float* __restrict__ b1,
                                               const float* __restrict__ dinv,
                                               unsigned short* __restrict__ C) {
    constexpr int K = 128, N = 256;
    int w = threadIdx.x >> 6, l = threadIdx.x & 63;
    int lm = l & 15, lq = l >> 4;
    int m0 = blockIdx.x * 64;
    int n0 = w * 64;
    f32x4 acc[4][4] = {};
    const unsigned short* Ab = A + (size_t)(m0 + lm) * K + lq * 8;
    const unsigned short* Bb = W1t + (size_t)(n0 + lm) * K + lq * 8;
    bfrag afb[2][4];
#pragma unroll
    for (int i = 0; i < 4; ++i) afb[0][i] = *(const bfrag*)(Ab + (size_t)i * 16 * K);
#pragma unroll
    for (int it = 0; it < K / 32; ++it) {
        int ks = it * 32;
        int cur = it & 1;
        if (it + 1 < K / 32) {
#pragma unroll
            for (int i = 0; i < 4; ++i)
                afb[cur ^ 1][i] = *(const bfrag*)(Ab + (size_t)i * 16 * K + ks + 32);
        }
        bfrag bf[4];
#pragma unroll
        for (int j = 0; j < 4; ++j) bf[j] = *(const bfrag*)(Bb + (size_t)j * 16 * K + ks);
#pragma unroll
        for (int i = 0; i < 4; ++i)
#pragma unroll
            for (int j = 0; j < 4; ++j)
                acc[i][j] = __builtin_amdgcn_mfma_f32_16x16x32_bf16(afb[cur][i], bf[j], acc[i][j], 0, 0, 0);
    }
    float bj[4];
#pragma unroll
    for (int j = 0; j < 4; ++j) bj[j] = b1[n0 + j * 16 + lm];
    int row0 = lq * 4;
    float drow[4][4];
#pragma unroll
    for (int i = 0; i < 4; ++i)
#pragma unroll
        for (int r = 0; r < 4; ++r) drow[i][r] = dinv[m0 + i * 16 + row0 + r];
#pragma unroll
    for (int i = 0; i < 4; ++i)
#pragma unroll
        for (int j = 0; j < 4; ++j)
#pragma unroll
            for (int r = 0; r < 4; ++r) {
                float v = tanhf(acc[i][j][r] + bj[j]) * drow[i][r];
                C[(size_t)(m0 + i * 16 + row0 + r) * N + n0 + j * 16 + lm] = f2bf(v);
            }
}

// ---------------- fused layers 2+3 GEMM:
// C2[64,256] = tanh(A[64,256] @ W2 + b2)  (per 64-row block, via LDS)
// C3[64,128] = (C2 @ W3) * dinv  -> output for agg3
// Stage 1: 4 waves x (64x64); stage 2: 4 waves x (64x32).

__global__ __launch_bounds__(256) void k_gemm23(const unsigned short* __restrict__ A,
                                                const unsigned short* __restrict__ W2t,
                                                const float* __restrict__ b2,
                                                const unsigned short* __restrict__ W3t,
                                                const float* __restrict__ dinv,
                                                unsigned short* __restrict__ C) {
    constexpr int K = 256, N3 = 128;
    __shared__ unsigned short c2[64][264];   // 264 = 256 + 8 pad (bank spread)
    int w = threadIdx.x >> 6, l = threadIdx.x & 63;
    int lm = l & 15, lq = l >> 4;
    int m0 = blockIdx.x * 64;
    int n0 = w * 64;
    int row0 = lq * 4;
    // ---- stage 1: C2 tile ----
    {
        f32x4 acc[4][4] = {};
        const unsigned short* Ab = A + (size_t)(m0 + lm) * K + lq * 8;
        const unsigned short* Bb = W2t + (size_t)(n0 + lm) * K + lq * 8;
        bfrag afb[2][4];
#pragma unroll
        for (int i = 0; i < 4; ++i) afb[0][i] = *(const bfrag*)(Ab + (size_t)i * 16 * K);
#pragma unroll
        for (int it = 0; it < K / 32; ++it) {
            int ks = it * 32;
            int cur = it & 1;
            if (it + 1 < K / 32) {
#pragma unroll
                for (int i = 0; i < 4; ++i)
                    afb[cur ^ 1][i] = *(const bfrag*)(Ab + (size_t)i * 16 * K + ks + 32);
            }
            bfrag bf[4];
#pragma unroll
            for (int j = 0; j < 4; ++j) bf[j] = *(const bfrag*)(Bb + (size_t)j * 16 * K + ks);
#pragma unroll
            for (int i = 0; i < 4; ++i)
#pragma unroll
                for (int j = 0; j < 4; ++j)
                    acc[i][j] = __builtin_amdgcn_mfma_f32_16x16x32_bf16(afb[cur][i], bf[j], acc[i][j], 0, 0, 0);
        }
        float bj[4];
#pragma unroll
        for (int j = 0; j < 4; ++j) bj[j] = b2[n0 + j * 16 + lm];
#pragma unroll
        for (int i = 0; i < 4; ++i)
#pragma unroll
            for (int j = 0; j < 4; ++j)
#pragma unroll
                for (int r = 0; r < 4; ++r)
                    c2[i * 16 + row0 + r][n0 + j * 16 + lm] = f2bf(tanhf(acc[i][j][r] + bj[j]));
    }
    __syncthreads();
    // ---- stage 2: C3 = C2 @ W3 ----
    {
        f32x4 acc[4][2] = {};
        int n3 = w * 32;
        const unsigned short* Bb = W3t + (size_t)(n3 + lm) * K + lq * 8;
#pragma unroll
        for (int it = 0; it < K / 32; ++it) {
            int ks = it * 32;
            bfrag af[4], bf[2];
#pragma unroll
            for (int i = 0; i < 4; ++i) af[i] = *(const bfrag*)&c2[i * 16 + lm][ks + lq * 8];
#pragma unroll
            for (int j = 0; j < 2; ++j) bf[j] = *(const bfrag*)(Bb + (size_t)j * 16 * K + ks);
#pragma unroll
            for (int i = 0; i < 4; ++i)
#pragma unroll
                for (int j = 0; j < 2; ++j)
                    acc[i][j] = __builtin_amdgcn_mfma_f32_16x16x32_bf16(af[i], bf[j], acc[i][j], 0, 0, 0);
        }
        float drow[4][4];
#pragma unroll
        for (int i = 0; i < 4; ++i)
#pragma unroll
            for (int r = 0; r < 4; ++r) drow[i][r] = dinv[m0 + i * 16 + row0 + r];
#pragma unroll
        for (int i = 0; i < 4; ++i)
#pragma unroll
            for (int j = 0; j < 2; ++j)
#pragma unroll
                for (int r = 0; r < 4; ++r)
                    C[(size_t)(m0 + i * 16 + row0 + r) * N3 + n3 + j * 16 + lm] =
                        f2bf(acc[i][j][r] * drow[i][r]);
    }
}

// ---------------- final FC: out[64,64] = h[64,128000](bf16) @ Wfc[128000,64](f32) + bfc

__global__ void k_fc(const unsigned short* __restrict__ A, const float* __restrict__ B,
                     float* __restrict__ part) {
    __shared__ float As[16][68];
    __shared__ float Bs[16][68];
    const int KROW = NB * 128;         // 128000
    int t = threadIdx.x;
    int tx = t & 15, ty = t >> 4;
    int k0b = blockIdx.x * 256;
    float acc[4][4] = {};
    for (int k0 = k0b; k0 < k0b + 256; k0 += 16) {
        int arow = t >> 2, ak = (t & 3) << 2;
        uint2 ua = *(const uint2*)(A + (size_t)arow * KROW + k0 + ak);
        As[ak + 0][arow] = bf2f((unsigned short)(ua.x & 0xffff));
        As[ak + 1][arow] = bf2f((unsigned short)(ua.x >> 16));
        As[ak + 2][arow] = bf2f((unsigned short)(ua.y & 0xffff));
        As[ak + 3][arow] = bf2f((unsigned short)(ua.y >> 16));
        int bk = t >> 4, bn4 = (t & 15) << 2;
        *(float4*)&Bs[bk][bn4] = *(const float4*)(B + (size_t)(k0 + bk) * NOUT + bn4);
        __syncthreads();
#pragma unroll
        for (int kk = 0; kk < 16; ++kk) {
            float4 a = *(const float4*)&As[kk][ty << 2];
            float4 b = *(const float4*)&Bs[kk][tx << 2];
            acc[0][0] += a.x * b.x; acc[0][1] += a.x * b.y; acc[0][2] += a.x * b.z; acc[0][3] += a.x * b.w;
            acc[1][0] += a.y * b.x; acc[1][1] += a.y * b.y; acc[1][2] += a.y * b.z; acc[1][3] += a.y * b.w;
            acc[2][0] += a.z * b.x; acc[2][1] += a.z * b.y; acc[2][2] += a.z * b.z; acc[2][3] += a.z * b.w;
            acc[3][0] += a.w * b.x; acc[3][1] += a.w * b.y; acc[3][2] += a.w * b.z; acc[3][3] += a.w * b.w;
        }
        __syncthreads();
    }
    float* po = part + (size_t)blockIdx.x * (NG * NOUT);
#pragma unroll
    for (int i = 0; i < 4; ++i) {
        float4 r;
        r.x = acc[i][0]; r.y = acc[i][1]; r.z = acc[i][2]; r.w = acc[i][3];
        *(float4*)&po[((ty << 2) + i) * NOUT + (tx << 2)] = r;
    }
}

__global__ void k_fc_reduce(const float* __restrict__ part, const float* __restrict__ bfc,
                            float* __restrict__ out) {
    int i = blockIdx.x * blockDim.x + threadIdx.x;   // 4096 threads
    float s = bfc[i & 63];
    for (int b = 0; b < FC_SPLIT; ++b) s += part[(size_t)b * (NG * NOUT) + i];
    out[i] = s;
}

// ---------------- driver ----------------

static inline size_t align256(size_t x) { return (x + 255) & ~(size_t)255; }

extern "C" void kernel_launch(void* const* d_in, const int* in_sizes, int n_in,
                              void* d_out, int out_size, void* d_ws, size_t ws_size,
                              hipStream_t stream) {
    const float* x   = (const float*)d_in[0];
    const int*   ei  = (const int*)d_in[1];
    const int*   src = ei;
    const int*   dst = ei + N_EDGES;
    const float* W1  = (const float*)d_in[3];
    const float* b1  = (const float*)d_in[4];
    const float* W2  = (const float*)d_in[5];
    const float* b2  = (const float*)d_in[6];
    const float* W3  = (const float*)d_in[7];
    const float* b3  = (const float*)d_in[8];
    const float* Wfc = (const float*)d_in[9];
    const float* bfc = (const float*)d_in[10];
    float* out = (float*)d_out;

    char* w = (char*)d_ws;
    unsigned short* P0 = (unsigned short*)w; w += align256((size_t)N_NODES * 256 * 2);
    unsigned short* P1 = (unsigned short*)w; w += align256((size_t)N_NODES * 256 * 2);
    unsigned short* P2 = (unsigned short*)w; w += align256((size_t)N_NODES * 256 * 2);
    int* rowptr = (int*)w;      w += align256((size_t)N_NODES * 4);
    int* rowend = (int*)w;      w += align256((size_t)N_NODES * 4);
    float* dinv = (float*)w;    w += align256((size_t)N_NODES * 4);
    int* gcnt = (int*)w;        w += align256((size_t)NG * 4);
    unsigned int* bucket = (unsigned int*)w; w += align256((size_t)NG * BK_CAP * 4);
    unsigned short* colp = (unsigned short*)w; w += align256((size_t)NG * BK_CAP * 2);
    float* fcpart = (float*)w;  w += align256((size_t)FC_SPLIT * NG * NOUT * 4);
    unsigned short* W1t = (unsigned short*)w; w += align256((size_t)128 * 256 * 2);
    unsigned short* W2t = (unsigned short*)w; w += align256((size_t)256 * 256 * 2);
    unsigned short* W3t = (unsigned short*)w; w += align256((size_t)256 * 128 * 2);

    // CSR build: bucket by graph, then per-graph local build
    hipMemsetAsync(gcnt, 0, (size_t)NG * 4, stream);
    k_bucket<<<N_EDGES / 4096, 256, 0, stream>>>(src, dst, gcnt, bucket);
    k_build<<<NG, 1024, 0, stream>>>(gcnt, bucket, rowptr, rowend, dinv, colp);

    // casts
    k_cast_scale<<<(N_NODES * 128 / 4) / 256, 256, 0, stream>>>(x, dinv, P0);
    k_wt<<<(128 * 256 + 255) / 256, 256, 0, stream>>>(W1, W1t, 128, 256);
    k_wt<<<(256 * 256 + 255) / 256, 256, 0, stream>>>(W2, W2t, 256, 256);
    k_wt<<<(256 * 128 + 255) / 256, 256, 0, stream>>>(W3, W3t, 256, 128);

    // layer 1: agg(H=128), gemm1 (tanh+b1+prescale) -> P2 (H=256)
    k_agg<128, false><<<N_NODES / 4, 256, 0, stream>>>(P0, P1, rowptr, rowend, colp, dinv, nullptr);
    k_gemm1<<<N_NODES / 64, 256, 0, stream>>>(P1, W1t, b1, dinv, P2);

    // layer 2: agg(H=256) -> P0; fused gemm2+gemm3 -> P1 (H=128, prescaled)
    k_agg<256, false><<<N_NODES / 4, 256, 0, stream>>>(P2, P0, rowptr, rowend, colp, dinv, nullptr);
    k_gemm23<<<N_NODES / 64, 256, 0, stream>>>(P0, W2t, b2, W3t, dinv, P1);

    // layer 3 aggregation: agg(H=128) + b3 + tanh -> P0
    k_agg<128, true><<<N_NODES / 4, 256, 0, stream>>>(P1, P0, rowptr, rowend, colp, dinv, b3);

    // final FC
    k_fc<<<FC_SPLIT, 256, 0, stream>>>(P0, Wfc, fcpart);
    k_fc_reduce<<<NG * NOUT / 256, 256, 0, stream>>>(fcpart, bfc, out);
}

// Round 8
// 349.970 us; speedup vs baseline: 2.9522x; 1.1952x over previous
//
#include <hip/hip_runtime.h>
#include <math.h>

#define N_NODES 64000
#define N_EDGES 1048576
#define NB 1000
#define NG 64
#define NOUT 64
#define FC_SPLIT 500      // 500 x 256 = 128000 K-rows
#define BK_CAP 18000      // per-graph edge bucket capacity (mean 16384, +12.7 sigma)

typedef __attribute__((ext_vector_type(8))) short bfrag;   // 8 bf16 = 4 VGPRs
typedef __attribute__((ext_vector_type(4))) float f32x4;

__device__ inline float bf2f(unsigned short u) {
    union { unsigned int i; float f; } x; x.i = ((unsigned int)u) << 16; return x.f;
}
__device__ inline float bflo(unsigned int u) {
    union { unsigned int i; float f; } x; x.i = u << 16; return x.f;
}
__device__ inline float bfhi(unsigned int u) {
    union { unsigned int i; float f; } x; x.i = u & 0xffff0000u; return x.f;
}
__device__ inline unsigned short f2bf(float f) {   // round-to-nearest-even
    union { float f; unsigned int i; } x; x.f = f;
    return (unsigned short)((x.i + 0x7FFFu + ((x.i >> 16) & 1u)) >> 16);
}

// ---------------- CSR build, graph-bucketed ----------------

__global__ __launch_bounds__(256) void k_bucket(const int* __restrict__ src,
                                                const int* __restrict__ dst,
                                                int* __restrict__ gcnt,
                                                unsigned int* __restrict__ bucket) {
    __shared__ int lcnt[64];
    __shared__ int lbase[64];
    __shared__ int lcur[64];
    int t = threadIdx.x;
    int e0 = blockIdx.x * 4096;
    if (t < 64) { lcnt[t] = 0; lcur[t] = 0; }
    __syncthreads();
    for (int i = t; i < 4096; i += 256) {
        int d = dst[e0 + i];
        int g = d / NB;
        atomicAdd(&lcnt[g], 1);
    }
    __syncthreads();
    if (t < 64) lbase[t] = atomicAdd(&gcnt[t], lcnt[t]);
    __syncthreads();
    for (int i = t; i < 4096; i += 256) {
        int d = dst[e0 + i];
        int s = src[e0 + i];
        int g = d / NB;
        int pos = atomicAdd(&lcur[g], 1);
        unsigned int packed = ((unsigned int)(d - g * NB) << 10) | (unsigned int)(s - g * NB);
        bucket[(size_t)g * BK_CAP + lbase[g] + pos] = packed;
    }
}

__global__ __launch_bounds__(1024) void k_build(const int* __restrict__ gcnt,
                                                const unsigned int* __restrict__ bucket,
                                                int* __restrict__ rowptr,
                                                int* __restrict__ rowend,
                                                float* __restrict__ dinv,
                                                unsigned short* __restrict__ colp) {
    __shared__ int ind[1024];
    __shared__ int tmp[1024];
    int t = threadIdx.x;
    int g = blockIdx.x;
    int cnt = gcnt[g];
    size_t base = (size_t)g * BK_CAP;
    ind[t] = 0;
    __syncthreads();
    for (int i = t; i < cnt; i += 1024) {
        unsigned int p = bucket[base + i];
        atomicAdd(&ind[p >> 10], 1);
    }
    __syncthreads();
    int deg = ind[t];
    if (t < NB) dinv[g * NB + t] = rsqrtf((float)(deg + 1));
    tmp[t] = deg;
    __syncthreads();
    for (int off = 1; off < 1024; off <<= 1) {
        int o = (t >= off) ? tmp[t - off] : 0;
        __syncthreads();
        tmp[t] += o;
        __syncthreads();
    }
    int excl = tmp[t] - deg;
    if (t < NB) {
        rowptr[g * NB + t] = (int)base + excl;
        rowend[g * NB + t] = (int)base + excl + deg;
    }
    ind[t] = excl;           // reuse as cursor
    __syncthreads();
    for (int i = t; i < cnt; i += 1024) {
        unsigned int p = bucket[base + i];
        int dl = p >> 10;
        int pos = atomicAdd(&ind[dl], 1);
        colp[base + pos] = (unsigned short)(p & 1023u);
    }
}

// ---------------- casts ----------------

__global__ void k_cast_scale(const float* __restrict__ in, const float* __restrict__ dinv,
                             unsigned short* __restrict__ out) {
    int i = (blockIdx.x * blockDim.x + threadIdx.x) * 4;
    float d = dinv[i >> 7];
    float4 v = *(const float4*)(in + i);
    union { unsigned short s[4]; uint2 u; } o;
    o.s[0] = f2bf(v.x * d); o.s[1] = f2bf(v.y * d);
    o.s[2] = f2bf(v.z * d); o.s[3] = f2bf(v.w * d);
    *(uint2*)(out + i) = o.u;
}

// W[K][N] fp32 -> Wt[N][K] bf16
__global__ void k_wt(const float* __restrict__ W, unsigned short* __restrict__ Wt,
                     int K, int N) {
    int i = blockIdx.x * 256 + threadIdx.x;
    if (i < K * N) {
        int n = i / K, k = i % K;
        Wt[i] = f2bf(W[k * N + n]);
    }
}

// ---------------- pull aggregation (bf16 in / bf16 out, fp32 math) ----------------
// readlane (uniform) -> scalar neighbor base, x4 batched independent gathers.

template <int H, bool TANH>
__global__ void k_agg(const unsigned short* __restrict__ hs, unsigned short* __restrict__ op,
                      const int* __restrict__ rowptr, const int* __restrict__ rowend,
                      const unsigned short* __restrict__ col,
                      const float* __restrict__ dinv, const float* __restrict__ bias) {
    constexpr int VEC = H / 64;
    int lane = threadIdx.x & 63;
    int b = blockIdx.x;
    int c = b & 7;
    int j = b >> 3;
    int g = c + 8 * (j / 250);
    int chunk = j % 250;
    int v = g * NB + chunk * 4 + (threadIdx.x >> 6);
    const unsigned short* gb = hs + (size_t)g * NB * H;
    float acc[VEC];
    {
        const unsigned short* r = hs + (size_t)v * H + lane * VEC;
        if (VEC == 2) {
            unsigned int u = *(const unsigned int*)r;
            acc[0] = bflo(u); acc[1] = bfhi(u);
        } else {
            uint2 u = *(const uint2*)r;
            acc[0] = bflo(u.x); acc[1] = bfhi(u.x);
            acc[2] = bflo(u.y); acc[3] = bfhi(u.y);
        }
    }
    int beg = rowptr[v], end = rowend[v];
    for (int e0 = beg; e0 < end; e0 += 64) {
        int me = e0 + lane;
        int s = (me < end) ? (int)col[me] : 0;
        int cnt = min(64, end - e0);
        int i = 0;
        for (; i + 4 <= cnt; i += 4) {
            int s0 = __builtin_amdgcn_readlane(s, i);
            int s1 = __builtin_amdgcn_readlane(s, i + 1);
            int s2 = __builtin_amdgcn_readlane(s, i + 2);
            int s3 = __builtin_amdgcn_readlane(s, i + 3);
            if (VEC == 2) {
                unsigned int u0 = *(const unsigned int*)(gb + (size_t)s0 * H + lane * 2);
                unsigned int u1 = *(const unsigned int*)(gb + (size_t)s1 * H + lane * 2);
                unsigned int u2 = *(const unsigned int*)(gb + (size_t)s2 * H + lane * 2);
                unsigned int u3 = *(const unsigned int*)(gb + (size_t)s3 * H + lane * 2);
                acc[0] += bflo(u0); acc[1] += bfhi(u0);
                acc[0] += bflo(u1); acc[1] += bfhi(u1);
                acc[0] += bflo(u2); acc[1] += bfhi(u2);
                acc[0] += bflo(u3); acc[1] += bfhi(u3);
            } else {
                uint2 u0 = *(const uint2*)(gb + (size_t)s0 * H + lane * 4);
                uint2 u1 = *(const uint2*)(gb + (size_t)s1 * H + lane * 4);
                uint2 u2 = *(const uint2*)(gb + (size_t)s2 * H + lane * 4);
                uint2 u3 = *(const uint2*)(gb + (size_t)s3 * H + lane * 4);
                acc[0] += bflo(u0.x); acc[1] += bfhi(u0.x); acc[2] += bflo(u0.y); acc[3] += bfhi(u0.y);
                acc[0] += bflo(u1.x); acc[1] += bfhi(u1.x); acc[2] += bflo(u1.y); acc[3] += bfhi(u1.y);
                acc[0] += bflo(u2.x); acc[1] += bfhi(u2.x); acc[2] += bflo(u2.y); acc[3] += bfhi(u2.y);
                acc[0] += bflo(u3.x); acc[1] += bfhi(u3.x); acc[2] += bflo(u3.y); acc[3] += bfhi(u3.y);
            }
        }
        for (; i < cnt; ++i) {
            int ss = __builtin_amdgcn_readlane(s, i);
            if (VEC == 2) {
                unsigned int u = *(const unsigned int*)(gb + (size_t)ss * H + lane * 2);
                acc[0] += bflo(u); acc[1] += bfhi(u);
            } else {
                uint2 u = *(const uint2*)(gb + (size_t)ss * H + lane * 4);
                acc[0] += bflo(u.x); acc[1] += bfhi(u.x);
                acc[2] += bflo(u.y); acc[3] += bfhi(u.y);
            }
        }
    }
    float dv = dinv[v];
    if (TANH) {
#pragma unroll
        for (int q = 0; q < VEC; ++q) acc[q] = tanhf(acc[q] * dv + bias[lane * VEC + q]);
    } else {
#pragma unroll
        for (int q = 0; q < VEC; ++q) acc[q] *= dv;
    }
    unsigned short* o = op + (size_t)v * H + lane * VEC;
    if (VEC == 2) {
        union { unsigned short s[2]; unsigned int u; } pk;
        pk.s[0] = f2bf(acc[0]); pk.s[1] = f2bf(acc[1]);
        *(unsigned int*)o = pk.u;
    } else {
        union { unsigned short s[4]; uint2 u; } pk;
        pk.s[0] = f2bf(acc[0]); pk.s[1] = f2bf(acc[1]);
        pk.s[2] = f2bf(acc[2]); pk.s[3] = f2bf(acc[3]);
        *(uint2*)o = pk.u;
    }
}

// ---------------- layer-1 GEMM: C[64000,256] = tanh(A[64000,128] @ W1 + b1) * dinv
// A-tile (64x128) staged cooperatively in padded LDS (stride 136 -> uniform banks),
// shared by all 4 waves; B-frags register-double-buffered.

__global__ __launch_bounds__(256) void k_gemm1(const unsigned short* __restrict__ A,
                                               const unsigned short* __restrict__ W1t,
                                               const float* __restrict__ b1,
                                               const float* __restrict__ dinv,
                                               unsigned short* __restrict__ C) {
    constexpr int K = 128, N = 256;
    __shared__ unsigned short at[64 * 136];
    int t = threadIdx.x;
    int w = t >> 6, l = t & 63;
    int lm = l & 15, lq = l >> 4;
    int m0 = blockIdx.x * 64;
    int n0 = w * 64;
    {   // stage A: thread t -> row t>>2, 32-short chunk (t&3)*32
        int row = t >> 2, kc = (t & 3) * 32;
        const unsigned short* gr = A + (size_t)(m0 + row) * K + kc;
        unsigned short* lr = at + row * 136 + kc;
        uint4 v0 = *(const uint4*)(gr);
        uint4 v1 = *(const uint4*)(gr + 8);
        uint4 v2 = *(const uint4*)(gr + 16);
        uint4 v3 = *(const uint4*)(gr + 24);
        *(uint4*)(lr) = v0; *(uint4*)(lr + 8) = v1;
        *(uint4*)(lr + 16) = v2; *(uint4*)(lr + 24) = v3;
    }
    __syncthreads();
    f32x4 acc[4][4] = {};
    const unsigned short* Bb = W1t + (size_t)(n0 + lm) * K + lq * 8;
    bfrag bfb[2][4];
#pragma unroll
    for (int j = 0; j < 4; ++j) bfb[0][j] = *(const bfrag*)(Bb + (size_t)j * 16 * K);
#pragma unroll
    for (int it = 0; it < K / 32; ++it) {
        int ks = it * 32, cur = it & 1;
        if (it + 1 < K / 32) {
#pragma unroll
            for (int j = 0; j < 4; ++j)
                bfb[cur ^ 1][j] = *(const bfrag*)(Bb + (size_t)j * 16 * K + ks + 32);
        }
        bfrag af[4];
#pragma unroll
        for (int i = 0; i < 4; ++i) af[i] = *(const bfrag*)&at[(i * 16 + lm) * 136 + ks + lq * 8];
#pragma unroll
        for (int i = 0; i < 4; ++i)
#pragma unroll
            for (int j = 0; j < 4; ++j)
                acc[i][j] = __builtin_amdgcn_mfma_f32_16x16x32_bf16(af[i], bfb[cur][j], acc[i][j], 0, 0, 0);
    }
    float bj[4];
#pragma unroll
    for (int j = 0; j < 4; ++j) bj[j] = b1[n0 + j * 16 + lm];
    int row0 = lq * 4;
    float drow[4][4];
#pragma unroll
    for (int i = 0; i < 4; ++i)
#pragma unroll
        for (int r = 0; r < 4; ++r) drow[i][r] = dinv[m0 + i * 16 + row0 + r];
#pragma unroll
    for (int i = 0; i < 4; ++i)
#pragma unroll
        for (int j = 0; j < 4; ++j)
#pragma unroll
            for (int r = 0; r < 4; ++r) {
                float v = tanhf(acc[i][j][r] + bj[j]) * drow[i][r];
                C[(size_t)(m0 + i * 16 + row0 + r) * N + n0 + j * 16 + lm] = f2bf(v);
            }
}

// ---------------- fused layers 2+3 GEMM:
// stage A-tile (64x256) in padded LDS; stage1 C2 = tanh(A@W2+b2) -> same LDS buf
// (barrier-separated reuse); stage2 C3 = (C2@W3)*dinv.

__global__ __launch_bounds__(256) void k_gemm23(const unsigned short* __restrict__ A,
                                                const unsigned short* __restrict__ W2t,
                                                const float* __restrict__ b2,
                                                const unsigned short* __restrict__ W3t,
                                                const float* __restrict__ dinv,
                                                unsigned short* __restrict__ C) {
    constexpr int K = 256, N3 = 128;
    __shared__ unsigned short at[64 * 264];   // 33792 B; A-tile, then reused as C2
    int t = threadIdx.x;
    int w = t >> 6, l = t & 63;
    int lm = l & 15, lq = l >> 4;
    int m0 = blockIdx.x * 64;
    int n0 = w * 64;
    int row0 = lq * 4;
    {   // stage A: thread t -> row t>>2, 64-short chunk (t&3)*64
        int row = t >> 2, kc = (t & 3) * 64;
        const unsigned short* gr = A + (size_t)(m0 + row) * K + kc;
        unsigned short* lr = at + row * 264 + kc;
        uint4 v[8];
#pragma unroll
        for (int j = 0; j < 8; ++j) v[j] = *(const uint4*)(gr + j * 8);
#pragma unroll
        for (int j = 0; j < 8; ++j) *(uint4*)(lr + j * 8) = v[j];
    }
    __syncthreads();
    // ---- stage 1: C2 = tanh(A @ W2 + b2) ----
    f32x4 acc[4][4] = {};
    {
        const unsigned short* Bb = W2t + (size_t)(n0 + lm) * K + lq * 8;
        bfrag bfb[2][4];
#pragma unroll
        for (int j = 0; j < 4; ++j) bfb[0][j] = *(const bfrag*)(Bb + (size_t)j * 16 * K);
#pragma unroll
        for (int it = 0; it < K / 32; ++it) {
            int ks = it * 32, cur = it & 1;
            if (it + 1 < K / 32) {
#pragma unroll
                for (int j = 0; j < 4; ++j)
                    bfb[cur ^ 1][j] = *(const bfrag*)(Bb + (size_t)j * 16 * K + ks + 32);
            }
            bfrag af[4];
#pragma unroll
            for (int i = 0; i < 4; ++i) af[i] = *(const bfrag*)&at[(i * 16 + lm) * 264 + ks + lq * 8];
#pragma unroll
            for (int i = 0; i < 4; ++i)
#pragma unroll
                for (int j = 0; j < 4; ++j)
                    acc[i][j] = __builtin_amdgcn_mfma_f32_16x16x32_bf16(af[i], bfb[cur][j], acc[i][j], 0, 0, 0);
        }
    }
    __syncthreads();   // all stage-1 A-reads done; safe to overwrite with C2
    {
        float bj[4];
#pragma unroll
        for (int j = 0; j < 4; ++j) bj[j] = b2[n0 + j * 16 + lm];
#pragma unroll
        for (int i = 0; i < 4; ++i)
#pragma unroll
            for (int j = 0; j < 4; ++j)
#pragma unroll
                for (int r = 0; r < 4; ++r)
                    at[(i * 16 + row0 + r) * 264 + n0 + j * 16 + lm] =
                        f2bf(tanhf(acc[i][j][r] + bj[j]));
    }
    __syncthreads();
    // ---- stage 2: C3 = (C2 @ W3) * dinv ----
    {
        f32x4 acc2[4][2] = {};
        int n3 = w * 32;
        const unsigned short* Bb = W3t + (size_t)(n3 + lm) * K + lq * 8;
        bfrag bfb[2][2];
#pragma unroll
        for (int j = 0; j < 2; ++j) bfb[0][j] = *(const bfrag*)(Bb + (size_t)j * 16 * K);
#pragma unroll
        for (int it = 0; it < K / 32; ++it) {
            int ks = it * 32, cur = it & 1;
            if (it + 1 < K / 32) {
#pragma unroll
                for (int j = 0; j < 2; ++j)
                    bfb[cur ^ 1][j] = *(const bfrag*)(Bb + (size_t)j * 16 * K + ks + 32);
            }
            bfrag af[4];
#pragma unroll
            for (int i = 0; i < 4; ++i) af[i] = *(const bfrag*)&at[(i * 16 + lm) * 264 + ks + lq * 8];
#pragma unroll
            for (int i = 0; i < 4; ++i)
#pragma unroll
                for (int j = 0; j < 2; ++j)
                    acc2[i][j] = __builtin_amdgcn_mfma_f32_16x16x32_bf16(af[i], bfb[cur][j], acc2[i][j], 0, 0, 0);
        }
        float drow[4][4];
#pragma unroll
        for (int i = 0; i < 4; ++i)
#pragma unroll
            for (int r = 0; r < 4; ++r) drow[i][r] = dinv[m0 + i * 16 + row0 + r];
#pragma unroll
        for (int i = 0; i < 4; ++i)
#pragma unroll
            for (int j = 0; j < 2; ++j)
#pragma unroll
                for (int r = 0; r < 4; ++r)
                    C[(size_t)(m0 + i * 16 + row0 + r) * N3 + n3 + j * 16 + lm] =
                        f2bf(acc2[i][j][r] * drow[i][r]);
    }
}

// ---------------- final FC: out[64,64] = h[64,128000](bf16) @ Wfc[128000,64](f32) + bfc

__global__ void k_fc(const unsigned short* __restrict__ A, const float* __restrict__ B,
                     float* __restrict__ part) {
    __shared__ float As[16][68];
    __shared__ float Bs[16][68];
    const int KROW = NB * 128;         // 128000
    int t = threadIdx.x;
    int tx = t & 15, ty = t >> 4;
    int k0b = blockIdx.x * 256;
    float acc[4][4] = {};
    for (int k0 = k0b; k0 < k0b + 256; k0 += 16) {
        int arow = t >> 2, ak = (t & 3) << 2;
        uint2 ua = *(const uint2*)(A + (size_t)arow * KROW + k0 + ak);
        As[ak + 0][arow] = bflo(ua.x);
        As[ak + 1][arow] = bfhi(ua.x);
        As[ak + 2][arow] = bflo(ua.y);
        As[ak + 3][arow] = bfhi(ua.y);
        int bk = t >> 4, bn4 = (t & 15) << 2;
        *(float4*)&Bs[bk][bn4] = *(const float4*)(B + (size_t)(k0 + bk) * NOUT + bn4);
        __syncthreads();
#pragma unroll
        for (int kk = 0; kk < 16; ++kk) {
            float4 a = *(const float4*)&As[kk][ty << 2];
            float4 b = *(const float4*)&Bs[kk][tx << 2];
            acc[0][0] += a.x * b.x; acc[0][1] += a.x * b.y; acc[0][2] += a.x * b.z; acc[0][3] += a.x * b.w;
            acc[1][0] += a.y * b.x; acc[1][1] += a.y * b.y; acc[1][2] += a.y * b.z; acc[1][3] += a.y * b.w;
            acc[2][0] += a.z * b.x; acc[2][1] += a.z * b.y; acc[2][2] += a.z * b.z; acc[2][3] += a.z * b.w;
            acc[3][0] += a.w * b.x; acc[3][1] += a.w * b.y; acc[3][2] += a.w * b.z; acc[3][3] += a.w * b.w;
        }
        __syncthreads();
    }
    float* po = part + (size_t)blockIdx.x * (NG * NOUT);
#pragma unroll
    for (int i = 0; i < 4; ++i) {
        float4 r;
        r.x = acc[i][0]; r.y = acc[i][1]; r.z = acc[i][2]; r.w = acc[i][3];
        *(float4*)&po[((ty << 2) + i) * NOUT + (tx << 2)] = r;
    }
}

__global__ void k_fc_reduce(const float* __restrict__ part, const float* __restrict__ bfc,
                            float* __restrict__ out) {
    int i = blockIdx.x * blockDim.x + threadIdx.x;   // 4096 threads
    float s = bfc[i & 63];
    for (int b = 0; b < FC_SPLIT; ++b) s += part[(size_t)b * (NG * NOUT) + i];
    out[i] = s;
}

// ---------------- driver ----------------

static inline size_t align256(size_t x) { return (x + 255) & ~(size_t)255; }

extern "C" void kernel_launch(void* const* d_in, const int* in_sizes, int n_in,
                              void* d_out, int out_size, void* d_ws, size_t ws_size,
                              hipStream_t stream) {
    const float* x   = (const float*)d_in[0];
    const int*   ei  = (const int*)d_in[1];
    const int*   src = ei;
    const int*   dst = ei + N_EDGES;
    const float* W1  = (const float*)d_in[3];
    const float* b1  = (const float*)d_in[4];
    const float* W2  = (const float*)d_in[5];
    const float* b2  = (const float*)d_in[6];
    const float* W3  = (const float*)d_in[7];
    const float* b3  = (const float*)d_in[8];
    const float* Wfc = (const float*)d_in[9];
    const float* bfc = (const float*)d_in[10];
    float* out = (float*)d_out;

    char* w = (char*)d_ws;
    unsigned short* P0 = (unsigned short*)w; w += align256((size_t)N_NODES * 256 * 2);
    unsigned short* P1 = (unsigned short*)w; w += align256((size_t)N_NODES * 256 * 2);
    unsigned short* P2 = (unsigned short*)w; w += align256((size_t)N_NODES * 256 * 2);
    int* rowptr = (int*)w;      w += align256((size_t)N_NODES * 4);
    int* rowend = (int*)w;      w += align256((size_t)N_NODES * 4);
    float* dinv = (float*)w;    w += align256((size_t)N_NODES * 4);
    int* gcnt = (int*)w;        w += align256((size_t)NG * 4);
    unsigned int* bucket = (unsigned int*)w; w += align256((size_t)NG * BK_CAP * 4);
    unsigned short* colp = (unsigned short*)w; w += align256((size_t)NG * BK_CAP * 2);
    float* fcpart = (float*)w;  w += align256((size_t)FC_SPLIT * NG * NOUT * 4);
    unsigned short* W1t = (unsigned short*)w; w += align256((size_t)128 * 256 * 2);
    unsigned short* W2t = (unsigned short*)w; w += align256((size_t)256 * 256 * 2);
    unsigned short* W3t = (unsigned short*)w; w += align256((size_t)256 * 128 * 2);

    // CSR build
    hipMemsetAsync(gcnt, 0, (size_t)NG * 4, stream);
    k_bucket<<<N_EDGES / 4096, 256, 0, stream>>>(src, dst, gcnt, bucket);
    k_build<<<NG, 1024, 0, stream>>>(gcnt, bucket, rowptr, rowend, dinv, colp);

    // casts
    k_cast_scale<<<(N_NODES * 128 / 4) / 256, 256, 0, stream>>>(x, dinv, P0);
    k_wt<<<(128 * 256 + 255) / 256, 256, 0, stream>>>(W1, W1t, 128, 256);
    k_wt<<<(256 * 256 + 255) / 256, 256, 0, stream>>>(W2, W2t, 256, 256);
    k_wt<<<(256 * 128 + 255) / 256, 256, 0, stream>>>(W3, W3t, 256, 128);

    // layer 1: agg(H=128), gemm1 (tanh+b1+prescale) -> P2 (H=256)
    k_agg<128, false><<<N_NODES / 4, 256, 0, stream>>>(P0, P1, rowptr, rowend, colp, dinv, nullptr);
    k_gemm1<<<N_NODES / 64, 256, 0, stream>>>(P1, W1t, b1, dinv, P2);

    // layer 2: agg(H=256) -> P0; fused gemm2+gemm3 -> P1 (H=128, prescaled)
    k_agg<256, false><<<N_NODES / 4, 256, 0, stream>>>(P2, P0, rowptr, rowend, colp, dinv, nullptr);
    k_gemm23<<<N_NODES / 64, 256, 0, stream>>>(P0, W2t, b2, W3t, dinv, P1);

    // layer 3 aggregation: agg(H=128) + b3 + tanh -> P0
    k_agg<128, true><<<N_NODES / 4, 256, 0, stream>>>(P1, P0, rowptr, rowend, colp, dinv, b3);

    // final FC
    k_fc<<<FC_SPLIT, 256, 0, stream>>>(P0, Wfc, fcpart);
    k_fc_reduce<<<NG * NOUT / 256, 256, 0, stream>>>(fcpart, bfc, out);
}

// Round 9
// 348.924 us; speedup vs baseline: 2.9610x; 1.0030x over previous
//
#include <hip/hip_runtime.h>
#include <math.h>

#define N_NODES 64000
#define N_EDGES 1048576
#define NB 1000
#define NG 64
#define NOUT 64
#define FC_SPLIT 500      // 500 x 256 = 128000 K-rows
#define BK_CAP 18000      // per-graph edge bucket capacity (mean 16384, +12.7 sigma)

typedef __attribute__((ext_vector_type(8))) short bfrag;   // 8 bf16 = 4 VGPRs
typedef __attribute__((ext_vector_type(4))) float f32x4;
typedef __attribute__((ext_vector_type(2))) float f32x2;

__device__ inline float bf2f(unsigned short u) {
    union { unsigned int i; float f; } x; x.i = ((unsigned int)u) << 16; return x.f;
}
__device__ inline float bflo(unsigned int u) {
    union { unsigned int i; float f; } x; x.i = u << 16; return x.f;
}
__device__ inline float bfhi(unsigned int u) {
    union { unsigned int i; float f; } x; x.i = u & 0xffff0000u; return x.f;
}
__device__ inline f32x2 upk(unsigned int u) {   // {lo,hi} bf16 pair -> f32x2 (v_pk_add friendly)
    f32x2 r; r.x = bflo(u); r.y = bfhi(u); return r;
}
__device__ inline unsigned short f2bf(float f) {   // round-to-nearest-even
    union { float f; unsigned int i; } x; x.f = f;
    return (unsigned short)((x.i + 0x7FFFu + ((x.i >> 16) & 1u)) >> 16);
}
// XOR swizzle for 64x256-short LDS tile: 16B-group g of row -> physical group.
// Bijective per row; uniform bank spread for b128 reads AND staging writes.
__device__ inline int swz(int row, int g) { return g ^ (row & 7) ^ (g >> 3); }

// ---------------- CSR build, graph-bucketed ----------------

__global__ __launch_bounds__(256) void k_bucket(const int* __restrict__ src,
                                                const int* __restrict__ dst,
                                                int* __restrict__ gcnt,
                                                unsigned int* __restrict__ bucket) {
    __shared__ int lcnt[64];
    __shared__ int lbase[64];
    __shared__ int lcur[64];
    int t = threadIdx.x;
    int e0 = blockIdx.x * 4096;
    if (t < 64) { lcnt[t] = 0; lcur[t] = 0; }
    __syncthreads();
    for (int i = t; i < 4096; i += 256) {
        int d = dst[e0 + i];
        int g = d / NB;
        atomicAdd(&lcnt[g], 1);
    }
    __syncthreads();
    if (t < 64) lbase[t] = atomicAdd(&gcnt[t], lcnt[t]);
    __syncthreads();
    for (int i = t; i < 4096; i += 256) {
        int d = dst[e0 + i];
        int s = src[e0 + i];
        int g = d / NB;
        int pos = atomicAdd(&lcur[g], 1);
        unsigned int packed = ((unsigned int)(d - g * NB) << 10) | (unsigned int)(s - g * NB);
        bucket[(size_t)g * BK_CAP + lbase[g] + pos] = packed;
    }
}

__global__ __launch_bounds__(1024) void k_build(const int* __restrict__ gcnt,
                                                const unsigned int* __restrict__ bucket,
                                                int* __restrict__ rowptr,
                                                int* __restrict__ rowend,
                                                float* __restrict__ dinv,
                                                unsigned short* __restrict__ colp) {
    __shared__ int ind[1024];
    __shared__ int tmp[1024];
    int t = threadIdx.x;
    int g = blockIdx.x;
    int cnt = gcnt[g];
    size_t base = (size_t)g * BK_CAP;
    ind[t] = 0;
    __syncthreads();
    for (int i = t; i < cnt; i += 1024) {
        unsigned int p = bucket[base + i];
        atomicAdd(&ind[p >> 10], 1);
    }
    __syncthreads();
    int deg = ind[t];
    if (t < NB) dinv[g * NB + t] = rsqrtf((float)(deg + 1));
    tmp[t] = deg;
    __syncthreads();
    for (int off = 1; off < 1024; off <<= 1) {
        int o = (t >= off) ? tmp[t - off] : 0;
        __syncthreads();
        tmp[t] += o;
        __syncthreads();
    }
    int excl = tmp[t] - deg;
    if (t < NB) {
        rowptr[g * NB + t] = (int)base + excl;
        rowend[g * NB + t] = (int)base + excl + deg;
    }
    ind[t] = excl;           // reuse as cursor
    __syncthreads();
    for (int i = t; i < cnt; i += 1024) {
        unsigned int p = bucket[base + i];
        int dl = p >> 10;
        int pos = atomicAdd(&ind[dl], 1);
        colp[base + pos] = (unsigned short)(p & 1023u);
    }
}

// ---------------- casts ----------------

__global__ void k_cast_scale(const float* __restrict__ in, const float* __restrict__ dinv,
                             unsigned short* __restrict__ out) {
    int i = (blockIdx.x * blockDim.x + threadIdx.x) * 4;
    float d = dinv[i >> 7];
    float4 v = *(const float4*)(in + i);
    union { unsigned short s[4]; uint2 u; } o;
    o.s[0] = f2bf(v.x * d); o.s[1] = f2bf(v.y * d);
    o.s[2] = f2bf(v.z * d); o.s[3] = f2bf(v.w * d);
    *(uint2*)(out + i) = o.u;
}

// W[K][N] fp32 -> Wt[N][K] bf16
__global__ void k_wt(const float* __restrict__ W, unsigned short* __restrict__ Wt,
                     int K, int N) {
    int i = blockIdx.x * 256 + threadIdx.x;
    if (i < K * N) {
        int n = i / K, k = i % K;
        Wt[i] = f2bf(W[k * N + n]);
    }
}

// ---------------- pull aggregation (bf16 in / bf16 out, fp32 math) ----------------
// readlane (uniform) -> scalar neighbor base; x8 batched independent gathers;
// packed f32x2 accumulate (v_pk_add_f32).

template <int H, bool TANH>
__global__ void k_agg(const unsigned short* __restrict__ hs, unsigned short* __restrict__ op,
                      const int* __restrict__ rowptr, const int* __restrict__ rowend,
                      const unsigned short* __restrict__ col,
                      const float* __restrict__ dinv, const float* __restrict__ bias) {
    constexpr int VEC = H / 64;
    int lane = threadIdx.x & 63;
    int b = blockIdx.x;
    int c = b & 7;
    int j = b >> 3;
    int g = c + 8 * (j / 250);
    int chunk = j % 250;
    int v = g * NB + chunk * 4 + (threadIdx.x >> 6);
    const unsigned short* gb = hs + (size_t)g * NB * H;
    f32x2 a0, a1;
    {
        const unsigned short* r = hs + (size_t)v * H + lane * VEC;
        if (VEC == 2) {
            a0 = upk(*(const unsigned int*)r);
        } else {
            uint2 u = *(const uint2*)r;
            a0 = upk(u.x); a1 = upk(u.y);
        }
    }
    int beg = rowptr[v], end = rowend[v];
    for (int e0 = beg; e0 < end; e0 += 64) {
        int me = e0 + lane;
        int s = (me < end) ? (int)col[me] : 0;
        int cnt = min(64, end - e0);
        int i = 0;
        for (; i + 8 <= cnt; i += 8) {
            int sx[8];
#pragma unroll
            for (int q = 0; q < 8; ++q) sx[q] = __builtin_amdgcn_readlane(s, i + q);
            if (VEC == 2) {
                unsigned int u[8];
#pragma unroll
                for (int q = 0; q < 8; ++q)
                    u[q] = *(const unsigned int*)(gb + (size_t)sx[q] * H + lane * 2);
#pragma unroll
                for (int q = 0; q < 8; ++q) a0 += upk(u[q]);
            } else {
                uint2 u[8];
#pragma unroll
                for (int q = 0; q < 8; ++q)
                    u[q] = *(const uint2*)(gb + (size_t)sx[q] * H + lane * 4);
#pragma unroll
                for (int q = 0; q < 8; ++q) { a0 += upk(u[q].x); a1 += upk(u[q].y); }
            }
        }
        for (; i + 4 <= cnt; i += 4) {
            int sx[4];
#pragma unroll
            for (int q = 0; q < 4; ++q) sx[q] = __builtin_amdgcn_readlane(s, i + q);
            if (VEC == 2) {
                unsigned int u[4];
#pragma unroll
                for (int q = 0; q < 4; ++q)
                    u[q] = *(const unsigned int*)(gb + (size_t)sx[q] * H + lane * 2);
#pragma unroll
                for (int q = 0; q < 4; ++q) a0 += upk(u[q]);
            } else {
                uint2 u[4];
#pragma unroll
                for (int q = 0; q < 4; ++q)
                    u[q] = *(const uint2*)(gb + (size_t)sx[q] * H + lane * 4);
#pragma unroll
                for (int q = 0; q < 4; ++q) { a0 += upk(u[q].x); a1 += upk(u[q].y); }
            }
        }
        for (; i < cnt; ++i) {
            int ss = __builtin_amdgcn_readlane(s, i);
            if (VEC == 2) {
                a0 += upk(*(const unsigned int*)(gb + (size_t)ss * H + lane * 2));
            } else {
                uint2 u = *(const uint2*)(gb + (size_t)ss * H + lane * 4);
                a0 += upk(u.x); a1 += upk(u.y);
            }
        }
    }
    float dv = dinv[v];
    float acc[4];
    acc[0] = a0.x; acc[1] = a0.y;
    if (VEC == 4) { acc[2] = a1.x; acc[3] = a1.y; }
    if (TANH) {
#pragma unroll
        for (int q = 0; q < VEC; ++q) acc[q] = tanhf(acc[q] * dv + bias[lane * VEC + q]);
    } else {
#pragma unroll
        for (int q = 0; q < VEC; ++q) acc[q] *= dv;
    }
    unsigned short* o = op + (size_t)v * H + lane * VEC;
    if (VEC == 2) {
        union { unsigned short s[2]; unsigned int u; } pk;
        pk.s[0] = f2bf(acc[0]); pk.s[1] = f2bf(acc[1]);
        *(unsigned int*)o = pk.u;
    } else {
        union { unsigned short s[4]; uint2 u; } pk;
        pk.s[0] = f2bf(acc[0]); pk.s[1] = f2bf(acc[1]);
        pk.s[2] = f2bf(acc[2]); pk.s[3] = f2bf(acc[3]);
        *(uint2*)o = pk.u;
    }
}

// ---------------- layer-1 GEMM: C[64000,256] = tanh(A[64000,128] @ W1 + b1) * dinv
// A-tile (64x128) staged cooperatively in padded LDS, shared by all 4 waves.

__global__ __launch_bounds__(256) void k_gemm1(const unsigned short* __restrict__ A,
                                               const unsigned short* __restrict__ W1t,
                                               const float* __restrict__ b1,
                                               const float* __restrict__ dinv,
                                               unsigned short* __restrict__ C) {
    constexpr int K = 128, N = 256;
    __shared__ unsigned short at[64 * 136];
    int t = threadIdx.x;
    int w = t >> 6, l = t & 63;
    int lm = l & 15, lq = l >> 4;
    int m0 = blockIdx.x * 64;
    int n0 = w * 64;
    {   // stage A: thread t -> row t>>2, 32-short chunk (t&3)*32
        int row = t >> 2, kc = (t & 3) * 32;
        const unsigned short* gr = A + (size_t)(m0 + row) * K + kc;
        unsigned short* lr = at + row * 136 + kc;
        uint4 v0 = *(const uint4*)(gr);
        uint4 v1 = *(const uint4*)(gr + 8);
        uint4 v2 = *(const uint4*)(gr + 16);
        uint4 v3 = *(const uint4*)(gr + 24);
        *(uint4*)(lr) = v0; *(uint4*)(lr + 8) = v1;
        *(uint4*)(lr + 16) = v2; *(uint4*)(lr + 24) = v3;
    }
    __syncthreads();
    f32x4 acc[4][4] = {};
    const unsigned short* Bb = W1t + (size_t)(n0 + lm) * K + lq * 8;
    bfrag bfb[2][4];
#pragma unroll
    for (int j = 0; j < 4; ++j) bfb[0][j] = *(const bfrag*)(Bb + (size_t)j * 16 * K);
#pragma unroll
    for (int it = 0; it < K / 32; ++it) {
        int ks = it * 32, cur = it & 1;
        if (it + 1 < K / 32) {
#pragma unroll
            for (int j = 0; j < 4; ++j)
                bfb[cur ^ 1][j] = *(const bfrag*)(Bb + (size_t)j * 16 * K + ks + 32);
        }
        bfrag af[4];
#pragma unroll
        for (int i = 0; i < 4; ++i) af[i] = *(const bfrag*)&at[(i * 16 + lm) * 136 + ks + lq * 8];
#pragma unroll
        for (int i = 0; i < 4; ++i)
#pragma unroll
            for (int j = 0; j < 4; ++j)
                acc[i][j] = __builtin_amdgcn_mfma_f32_16x16x32_bf16(af[i], bfb[cur][j], acc[i][j], 0, 0, 0);
    }
    float bj[4];
#pragma unroll
    for (int j = 0; j < 4; ++j) bj[j] = b1[n0 + j * 16 + lm];
    int row0 = lq * 4;
    float drow[4][4];
#pragma unroll
    for (int i = 0; i < 4; ++i)
#pragma unroll
        for (int r = 0; r < 4; ++r) drow[i][r] = dinv[m0 + i * 16 + row0 + r];
#pragma unroll
    for (int i = 0; i < 4; ++i)
#pragma unroll
        for (int j = 0; j < 4; ++j)
#pragma unroll
            for (int r = 0; r < 4; ++r) {
                float v = tanhf(acc[i][j][r] + bj[j]) * drow[i][r];
                C[(size_t)(m0 + i * 16 + row0 + r) * N + n0 + j * 16 + lm] = f2bf(v);
            }
}

// ---------------- fused layers 2+3 GEMM:
// XOR-swizzled 32KB LDS A-tile (exactly 5 blocks/CU). stage1 C2 = tanh(A@W2+b2)
// written back into same buffer (barrier-separated); stage2 C3 = (C2@W3)*dinv.

__global__ __launch_bounds__(256) void k_gemm23(const unsigned short* __restrict__ A,
                                                const unsigned short* __restrict__ W2t,
                                                const float* __restrict__ b2,
                                                const unsigned short* __restrict__ W3t,
                                                const float* __restrict__ dinv,
                                                unsigned short* __restrict__ C) {
    constexpr int K = 256, N3 = 128;
    __shared__ unsigned short at[64 * 256];   // 32768 B, swizzled; A-tile then C2
    int t = threadIdx.x;
    int w = t >> 6, l = t & 63;
    int lm = l & 15, lq = l >> 4;
    int m0 = blockIdx.x * 64;
    int n0 = w * 64;
    int row0 = lq * 4;
    {   // stage A: thread t -> row t>>2, groups (t&3)*8 .. +7 (swizzled)
        int row = t >> 2, c = t & 3;
        const unsigned short* gr = A + (size_t)(m0 + row) * K + c * 64;
        unsigned short* lr = at + row * 256;
        uint4 v[8];
#pragma unroll
        for (int j = 0; j < 8; ++j) v[j] = *(const uint4*)(gr + j * 8);
#pragma unroll
        for (int j = 0; j < 8; ++j) {
            int gidx = c * 8 + j;
            *(uint4*)(lr + swz(row, gidx) * 8) = v[j];
        }
    }
    __syncthreads();
    // ---- stage 1: C2 = tanh(A @ W2 + b2) ----
    f32x4 acc[4][4] = {};
    {
        const unsigned short* Bb = W2t + (size_t)(n0 + lm) * K + lq * 8;
        bfrag bfb[2][4];
#pragma unroll
        for (int j = 0; j < 4; ++j) bfb[0][j] = *(const bfrag*)(Bb + (size_t)j * 16 * K);
#pragma unroll
        for (int it = 0; it < K / 32; ++it) {
            int ks = it * 32, cur = it & 1;
            if (it + 1 < K / 32) {
#pragma unroll
                for (int j = 0; j < 4; ++j)
                    bfb[cur ^ 1][j] = *(const bfrag*)(Bb + (size_t)j * 16 * K + ks + 32);
            }
            bfrag af[4];
            int gidx = it * 4 + lq;
#pragma unroll
            for (int i = 0; i < 4; ++i) {
                int row = i * 16 + lm;
                af[i] = *(const bfrag*)&at[row * 256 + swz(row, gidx) * 8];
            }
#pragma unroll
            for (int i = 0; i < 4; ++i)
#pragma unroll
                for (int j = 0; j < 4; ++j)
                    acc[i][j] = __builtin_amdgcn_mfma_f32_16x16x32_bf16(af[i], bfb[cur][j], acc[i][j], 0, 0, 0);
        }
    }
    __syncthreads();   // all stage-1 A-reads done; safe to overwrite with C2
    {
        float bj[4];
#pragma unroll
        for (int j = 0; j < 4; ++j) bj[j] = b2[n0 + j * 16 + lm];
#pragma unroll
        for (int i = 0; i < 4; ++i)
#pragma unroll
            for (int j = 0; j < 4; ++j) {
                int colb = n0 + j * 16 + lm;
                int gidx = colb >> 3, off = colb & 7;
#pragma unroll
                for (int r = 0; r < 4; ++r) {
                    int row = i * 16 + row0 + r;
                    at[row * 256 + swz(row, gidx) * 8 + off] =
                        f2bf(tanhf(acc[i][j][r] + bj[j]));
                }
            }
    }
    __syncthreads();
    // ---- stage 2: C3 = (C2 @ W3) * dinv ----
    {
        f32x4 acc2[4][2] = {};
        int n3 = w * 32;
        const unsigned short* Bb = W3t + (size_t)(n3 + lm) * K + lq * 8;
        bfrag bfb[2][2];
#pragma unroll
        for (int j = 0; j < 2; ++j) bfb[0][j] = *(const bfrag*)(Bb + (size_t)j * 16 * K);
#pragma unroll
        for (int it = 0; it < K / 32; ++it) {
            int ks = it * 32, cur = it & 1;
            if (it + 1 < K / 32) {
#pragma unroll
                for (int j = 0; j < 2; ++j)
                    bfb[cur ^ 1][j] = *(const bfrag*)(Bb + (size_t)j * 16 * K + ks + 32);
            }
            bfrag af[4];
            int gidx = it * 4 + lq;
#pragma unroll
            for (int i = 0; i < 4; ++i) {
                int row = i * 16 + lm;
                af[i] = *(const bfrag*)&at[row * 256 + swz(row, gidx) * 8];
            }
#pragma unroll
            for (int i = 0; i < 4; ++i)
#pragma unroll
                for (int j = 0; j < 2; ++j)
                    acc2[i][j] = __builtin_amdgcn_mfma_f32_16x16x32_bf16(af[i], bfb[cur][j], acc2[i][j], 0, 0, 0);
        }
        float drow[4][4];
#pragma unroll
        for (int i = 0; i < 4; ++i)
#pragma unroll
            for (int r = 0; r < 4; ++r) drow[i][r] = dinv[m0 + i * 16 + row0 + r];
#pragma unroll
        for (int i = 0; i < 4; ++i)
#pragma unroll
            for (int j = 0; j < 2; ++j)
#pragma unroll
                for (int r = 0; r < 4; ++r)
                    C[(size_t)(m0 + i * 16 + row0 + r) * N3 + n3 + j * 16 + lm] =
                        f2bf(acc2[i][j][r] * drow[i][r]);
    }
}

// ---------------- final FC: out[64,64] = h[64,128000](bf16) @ Wfc[128000,64](f32) + bfc

__global__ void k_fc(const unsigned short* __restrict__ A, const float* __restrict__ B,
                     float* __restrict__ part) {
    __shared__ float As[16][68];
    __shared__ float Bs[16][68];
    const int KROW = NB * 128;         // 128000
    int t = threadIdx.x;
    int tx = t & 15, ty = t >> 4;
    int k0b = blockIdx.x * 256;
    float acc[4][4] = {};
    for (int k0 = k0b; k0 < k0b + 256; k0 += 16) {
        int arow = t >> 2, ak = (t & 3) << 2;
        uint2 ua = *(const uint2*)(A + (size_t)arow * KROW + k0 + ak);
        As[ak + 0][arow] = bflo(ua.x);
        As[ak + 1][arow] = bfhi(ua.x);
        As[ak + 2][arow] = bflo(ua.y);
        As[ak + 3][arow] = bfhi(ua.y);
        int bk = t >> 4, bn4 = (t & 15) << 2;
        *(float4*)&Bs[bk][bn4] = *(const float4*)(B + (size_t)(k0 + bk) * NOUT + bn4);
        __syncthreads();
#pragma unroll
        for (int kk = 0; kk < 16; ++kk) {
            float4 a = *(const float4*)&As[kk][ty << 2];
            float4 b = *(const float4*)&Bs[kk][tx << 2];
            acc[0][0] += a.x * b.x; acc[0][1] += a.x * b.y; acc[0][2] += a.x * b.z; acc[0][3] += a.x * b.w;
            acc[1][0] += a.y * b.x; acc[1][1] += a.y * b.y; acc[1][2] += a.y * b.z; acc[1][3] += a.y * b.w;
            acc[2][0] += a.z * b.x; acc[2][1] += a.z * b.y; acc[2][2] += a.z * b.z; acc[2][3] += a.z * b.w;
            acc[3][0] += a.w * b.x; acc[3][1] += a.w * b.y; acc[3][2] += a.w * b.z; acc[3][3] += a.w * b.w;
        }
        __syncthreads();
    }
    float* po = part + (size_t)blockIdx.x * (NG * NOUT);
#pragma unroll
    for (int i = 0; i < 4; ++i) {
        float4 r;
        r.x = acc[i][0]; r.y = acc[i][1]; r.z = acc[i][2]; r.w = acc[i][3];
        *(float4*)&po[((ty << 2) + i) * NOUT + (tx << 2)] = r;
    }
}

__global__ void k_fc_reduce(const float* __restrict__ part, const float* __restrict__ bfc,
                            float* __restrict__ out) {
    int i = blockIdx.x * blockDim.x + threadIdx.x;   // 4096 threads
    float s = bfc[i & 63];
    for (int b = 0; b < FC_SPLIT; ++b) s += part[(size_t)b * (NG * NOUT) + i];
    out[i] = s;
}

// ---------------- driver ----------------

static inline size_t align256(size_t x) { return (x + 255) & ~(size_t)255; }

extern "C" void kernel_launch(void* const* d_in, const int* in_sizes, int n_in,
                              void* d_out, int out_size, void* d_ws, size_t ws_size,
                              hipStream_t stream) {
    const float* x   = (const float*)d_in[0];
    const int*   ei  = (const int*)d_in[1];
    const int*   src = ei;
    const int*   dst = ei + N_EDGES;
    const float* W1  = (const float*)d_in[3];
    const float* b1  = (const float*)d_in[4];
    const float* W2  = (const float*)d_in[5];
    const float* b2  = (const float*)d_in[6];
    const float* W3  = (const float*)d_in[7];
    const float* b3  = (const float*)d_in[8];
    const float* Wfc = (const float*)d_in[9];
    const float* bfc = (const float*)d_in[10];
    float* out = (float*)d_out;

    char* w = (char*)d_ws;
    unsigned short* P0 = (unsigned short*)w; w += align256((size_t)N_NODES * 256 * 2);
    unsigned short* P1 = (unsigned short*)w; w += align256((size_t)N_NODES * 256 * 2);
    unsigned short* P2 = (unsigned short*)w; w += align256((size_t)N_NODES * 256 * 2);
    int* rowptr = (int*)w;      w += align256((size_t)N_NODES * 4);
    int* rowend = (int*)w;      w += align256((size_t)N_NODES * 4);
    float* dinv = (float*)w;    w += align256((size_t)N_NODES * 4);
    int* gcnt = (int*)w;        w += align256((size_t)NG * 4);
    unsigned int* bucket = (unsigned int*)w; w += align256((size_t)NG * BK_CAP * 4);
    unsigned short* colp = (unsigned short*)w; w += align256((size_t)NG * BK_CAP * 2);
    float* fcpart = (float*)w;  w += align256((size_t)FC_SPLIT * NG * NOUT * 4);
    unsigned short* W1t = (unsigned short*)w; w += align256((size_t)128 * 256 * 2);
    unsigned short* W2t = (unsigned short*)w; w += align256((size_t)256 * 256 * 2);
    unsigned short* W3t = (unsigned short*)w; w += align256((size_t)256 * 128 * 2);

    // CSR build
    hipMemsetAsync(gcnt, 0, (size_t)NG * 4, stream);
    k_bucket<<<N_EDGES / 4096, 256, 0, stream>>>(src, dst, gcnt, bucket);
    k_build<<<NG, 1024, 0, stream>>>(gcnt, bucket, rowptr, rowend, dinv, colp);

    // casts
    k_cast_scale<<<(N_NODES * 128 / 4) / 256, 256, 0, stream>>>(x, dinv, P0);
    k_wt<<<(128 * 256 + 255) / 256, 256, 0, stream>>>(W1, W1t, 128, 256);
    k_wt<<<(256 * 256 + 255) / 256, 256, 0, stream>>>(W2, W2t, 256, 256);
    k_wt<<<(256 * 128 + 255) / 256, 256, 0, stream>>>(W3, W3t, 256, 128);

    // layer 1: agg(H=128), gemm1 (tanh+b1+prescale) -> P2 (H=256)
    k_agg<128, false><<<N_NODES / 4, 256, 0, stream>>>(P0, P1, rowptr, rowend, colp, dinv, nullptr);
    k_gemm1<<<N_NODES / 64, 256, 0, stream>>>(P1, W1t, b1, dinv, P2);

    // layer 2: agg(H=256) -> P0; fused gemm2+gemm3 -> P1 (H=128, prescaled)
    k_agg<256, false><<<N_NODES / 4, 256, 0, stream>>>(P2, P0, rowptr, rowend, colp, dinv, nullptr);
    k_gemm23<<<N_NODES / 64, 256, 0, stream>>>(P0, W2t, b2, W3t, dinv, P1);

    // layer 3 aggregation: agg(H=128) + b3 + tanh -> P0
    k_agg<128, true><<<N_NODES / 4, 256, 0, stream>>>(P1, P0, rowptr, rowend, colp, dinv, b3);

    // final FC
    k_fc<<<FC_SPLIT, 256, 0, stream>>>(P0, Wfc, fcpart);
    k_fc_reduce<<<NG * NOUT / 256, 256, 0, stream>>>(fcpart, bfc, out);
}